// Round 2
// baseline (5411.418 us; speedup 1.0000x reference)
//
#include <hip/hip_runtime.h>
#include <hip/hip_bf16.h>
#include <math.h>

typedef __hip_bfloat16 bf16;

__device__ __forceinline__ float b2f_us(unsigned short u) {
    unsigned int v = ((unsigned int)u) << 16;
    return __builtin_bit_cast(float, v);
}
__device__ __forceinline__ unsigned short f2b_us(float f) {
    return __builtin_bit_cast(unsigned short, __float2bfloat16(f));
}

__device__ __forceinline__ float4 ld4(const float* p) { return *(const float4*)p; }
__device__ __forceinline__ float4 ld4(const bf16* p) {
    ushort4 u = *(const ushort4*)p;
    return make_float4(b2f_us(u.x), b2f_us(u.y), b2f_us(u.z), b2f_us(u.w));
}
__device__ __forceinline__ void st4(float* p, float4 v) { *(float4*)p = v; }
__device__ __forceinline__ void st4(bf16* p, float4 v) {
    ushort4 o;
    o.x = f2b_us(v.x); o.y = f2b_us(v.y); o.z = f2b_us(v.z); o.w = f2b_us(v.w);
    *(ushort4*)p = o;
}

// ---------------------------------------------------------------- GN stats (x is f32)
__global__ __launch_bounds__(256) void gn_stats_k(const float* __restrict__ x,
                                                  float* __restrict__ stats) {
    int bg = blockIdx.x;                 // b*32 + g
    long base = (long)bg * 16384;        // 16 ch * 1024 spatial, contiguous
    int tid = threadIdx.x;
    float s = 0.f, sq = 0.f;
    for (int it = 0; it < 16; ++it) {
        float4 v = *(const float4*)(x + base + (long)it * 1024 + tid * 4);
        s += v.x + v.y + v.z + v.w;
        sq += v.x * v.x + v.y * v.y + v.z * v.z + v.w * v.w;
    }
#pragma unroll
    for (int off = 32; off; off >>= 1) {
        s += __shfl_down(s, off);
        sq += __shfl_down(sq, off);
    }
    __shared__ float r0[4], r1[4];
    if ((tid & 63) == 0) { r0[tid >> 6] = s; r1[tid >> 6] = sq; }
    __syncthreads();
    if (tid == 0) {
        s = r0[0] + r0[1] + r0[2] + r0[3];
        sq = r1[0] + r1[1] + r1[2] + r1[3];
        float mu = s * (1.f / 16384.f);
        float var = sq * (1.f / 16384.f) - mu * mu;
        stats[bg] = mu;
        stats[256 + bg] = rsqrtf(var + 1e-6f);
    }
}

// ---------------------------------------------------------------- LayerNorm (ws bf16 -> ws bf16)
__global__ __launch_bounds__(256) void ln_k(const bf16* __restrict__ in,
                                            const float* __restrict__ g,
                                            const float* __restrict__ bvec,
                                            bf16* __restrict__ out) {
    long row = blockIdx.x;
    const bf16* p = in + row * 512;
    int tid = threadIdx.x;
    float v0 = b2f_us(__builtin_bit_cast(unsigned short, p[tid]));
    float v1 = b2f_us(__builtin_bit_cast(unsigned short, p[tid + 256]));
    float s = v0 + v1, sq = v0 * v0 + v1 * v1;
#pragma unroll
    for (int off = 32; off; off >>= 1) {
        s += __shfl_down(s, off);
        sq += __shfl_down(sq, off);
    }
    __shared__ float r0[4], r1[4];
    if ((tid & 63) == 0) { r0[tid >> 6] = s; r1[tid >> 6] = sq; }
    __syncthreads();
    s = r0[0] + r0[1] + r0[2] + r0[3];
    sq = r1[0] + r1[1] + r1[2] + r1[3];
    float mu = s * (1.f / 512.f);
    float var = sq * (1.f / 512.f) - mu * mu;
    float rs = rsqrtf(var + 1e-5f);
    out[row * 512 + tid] = __float2bfloat16((v0 - mu) * rs * g[tid] + bvec[tid]);
    out[row * 512 + tid + 256] =
        __float2bfloat16((v1 - mu) * rs * g[tid + 256] + bvec[tid + 256]);
}

// ---------------------------------------------------------------- GEMM (f32 VALU, 64x64 tile)
constexpr int EPI_CIN = 0;      // GN-normalize A on load, +bias[n]
constexpr int EPI_PLAIN = 1;    // no bias
constexpr int EPI_BIASRES = 2;  // +bias[n] +res[m][n]
constexpr int EPI_CONVOUT = 3;  // +bias[m] +res[m][n]

template <int EPI, bool A_MCONT, bool B_NCONT, typename TA, typename TB,
          typename TR, typename TC>
__global__ __launch_bounds__(256) void gemm_k(
    const TA* __restrict__ Ag, const TB* __restrict__ Bg,
    const float* __restrict__ bias, const TR* __restrict__ resg,
    TC* __restrict__ Cg, int M, int N, int K,
    long sAm, long sAk, long sAb,
    long sBk, long sBn, long sBb,
    long sCb, long sRm, long sRb,
    const float* __restrict__ gnstats,
    const float* __restrict__ gng, const float* __restrict__ gnb) {
    const int b = blockIdx.z;
    const int m0 = blockIdx.y * 64, n0 = blockIdx.x * 64;
    const TA* A = Ag + (long)b * sAb;
    const TB* B = Bg + (long)b * sBb;
    __shared__ float Al[16][68];
    __shared__ float Bl[16][68];
    const int tid = threadIdx.x;
    const int tx = tid & 15, ty = tid >> 4;
    float acc[16] = {};

    for (int k0 = 0; k0 < K; k0 += 16) {
        if (A_MCONT) {  // m contiguous in memory: vector-load along m
            int m4 = (tid & 15) * 4, k = tid >> 4;
            const TA* p = A + (long)(k0 + k) * sAk + (long)(m0 + m4) * sAm;
            float4 v = ld4(p);
            if (EPI == EPI_CIN) {
                int c = k0 + k;
                float mu = gnstats[b * 32 + (c >> 4)];
                float rs = gnstats[256 + b * 32 + (c >> 4)];
                float ga = gng[c] * rs;
                float be = gnb[c] - mu * ga;
                v.x = v.x * ga + be; v.y = v.y * ga + be;
                v.z = v.z * ga + be; v.w = v.w * ga + be;
            }
            *(float4*)&Al[k][m4] = v;
        } else {  // k contiguous: vector-load along k
            int k4 = (tid & 3) * 4, m = tid >> 2;
            const TA* p = A + (long)(m0 + m) * sAm + (long)(k0 + k4) * sAk;
            float4 v = ld4(p);
            Al[k4 + 0][m] = v.x;
            Al[k4 + 1][m] = v.y;
            Al[k4 + 2][m] = v.z;
            Al[k4 + 3][m] = v.w;
        }
        if (B_NCONT) {
            int n4 = (tid & 15) * 4, k = tid >> 4;
            const TB* p = B + (long)(k0 + k) * sBk + (long)(n0 + n4) * sBn;
            *(float4*)&Bl[k][n4] = ld4(p);
        } else {
            int k4 = (tid & 3) * 4, n = tid >> 2;
            const TB* p = B + (long)(n0 + n) * sBn + (long)(k0 + k4) * sBk;
            float4 v = ld4(p);
            Bl[k4 + 0][n] = v.x;
            Bl[k4 + 1][n] = v.y;
            Bl[k4 + 2][n] = v.z;
            Bl[k4 + 3][n] = v.w;
        }
        __syncthreads();
#pragma unroll
        for (int kk = 0; kk < 16; ++kk) {
            float4 a4 = *(const float4*)&Al[kk][ty * 4];
            float4 b4 = *(const float4*)&Bl[kk][tx * 4];
            float av[4] = {a4.x, a4.y, a4.z, a4.w};
            float bv[4] = {b4.x, b4.y, b4.z, b4.w};
#pragma unroll
            for (int i = 0; i < 4; ++i)
#pragma unroll
                for (int j = 0; j < 4; ++j)
                    acc[i * 4 + j] = fmaf(av[i], bv[j], acc[i * 4 + j]);
        }
        __syncthreads();
    }
#pragma unroll
    for (int i = 0; i < 4; ++i) {
        int row = m0 + ty * 4 + i;
        float vals[4];
#pragma unroll
        for (int j = 0; j < 4; ++j) vals[j] = acc[i * 4 + j];
        if (EPI == EPI_CIN || EPI == EPI_BIASRES) {
            float4 bi4 = *(const float4*)(bias + n0 + tx * 4);
            vals[0] += bi4.x; vals[1] += bi4.y;
            vals[2] += bi4.z; vals[3] += bi4.w;
        }
        if (EPI == EPI_CONVOUT) {
            float bm = bias[row];
            vals[0] += bm; vals[1] += bm; vals[2] += bm; vals[3] += bm;
        }
        if (EPI == EPI_BIASRES || EPI == EPI_CONVOUT) {
            float4 r4 = ld4(resg + (long)b * sRb + (long)row * sRm + n0 + tx * 4);
            vals[0] += r4.x; vals[1] += r4.y;
            vals[2] += r4.z; vals[3] += r4.w;
        }
        st4(Cg + (long)b * sCb + (long)row * N + n0 + tx * 4,
            make_float4(vals[0], vals[1], vals[2], vals[3]));
    }
}

// ---------------------------------------------------------------- GEGLU GEMM (g1 + gelu-gate)
__global__ __launch_bounds__(256) void gemm_geglu(const bf16* __restrict__ Ag,
                                                  const float* __restrict__ Bg,
                                                  const float* __restrict__ bias,
                                                  bf16* __restrict__ Cg) {
    const int b = blockIdx.z;
    const int n0 = blockIdx.x * 64, m0 = blockIdx.y * 64;
    const bf16* A = Ag + (long)b * 1024 * 512;
    __shared__ float Al[16][68], Bv[16][68], Bg2[16][68];
    const int tid = threadIdx.x, tx = tid & 15, ty = tid >> 4;
    float accv[16] = {}, accg[16] = {};
    for (int k0 = 0; k0 < 512; k0 += 16) {
        {
            int k4 = (tid & 3) * 4, m = tid >> 2;
            float4 v = ld4(A + (long)(m0 + m) * 512 + k0 + k4);
            Al[k4 + 0][m] = v.x;
            Al[k4 + 1][m] = v.y;
            Al[k4 + 2][m] = v.z;
            Al[k4 + 3][m] = v.w;
        }
        {
            int n4 = (tid & 15) * 4, k = tid >> 4;
            const float* p = Bg + (long)(k0 + k) * 4096 + n0 + n4;
            *(float4*)&Bv[k][n4] = *(const float4*)p;
            *(float4*)&Bg2[k][n4] = *(const float4*)(p + 2048);
        }
        __syncthreads();
#pragma unroll
        for (int kk = 0; kk < 16; ++kk) {
            float4 a4 = *(const float4*)&Al[kk][ty * 4];
            float4 v4 = *(const float4*)&Bv[kk][tx * 4];
            float4 g4 = *(const float4*)&Bg2[kk][tx * 4];
            float av[4] = {a4.x, a4.y, a4.z, a4.w};
            float bv[4] = {v4.x, v4.y, v4.z, v4.w};
            float bg[4] = {g4.x, g4.y, g4.z, g4.w};
#pragma unroll
            for (int i = 0; i < 4; ++i)
#pragma unroll
                for (int j = 0; j < 4; ++j) {
                    accv[i * 4 + j] = fmaf(av[i], bv[j], accv[i * 4 + j]);
                    accg[i * 4 + j] = fmaf(av[i], bg[j], accg[i * 4 + j]);
                }
        }
        __syncthreads();
    }
#pragma unroll
    for (int i = 0; i < 4; ++i) {
        int row = m0 + ty * 4 + i;
        ushort4 o4;
#pragma unroll
        for (int j = 0; j < 4; ++j) {
            int n = n0 + tx * 4 + j;
            float v = accv[i * 4 + j] + bias[n];
            float g = accg[i * 4 + j] + bias[2048 + n];
            float gl = 0.5f * g * (1.f + erff(g * 0.70710678118654752f));
            ((unsigned short*)&o4)[j] = f2b_us(v * gl);
        }
        *(ushort4*)(Cg + (long)b * 1024 * 2048 + (long)row * 2048 + n0 + tx * 4) = o4;
    }
}

// ---------------------------------------------------------------- fused attention (8 q-rows/block)
__global__ __launch_bounds__(256) void attn_k(const bf16* __restrict__ qkv,
                                              bf16* __restrict__ o) {
    const int q0 = blockIdx.x * 8;
    const int h = blockIdx.y;
    const int b = blockIdx.z;
    const int tid = threadIdx.x;
    __shared__ float sc[8][1024];
    __shared__ float ql[8][64];
    __shared__ float vl[64][64];
    __shared__ float red[4];
    const bf16* basep = qkv + ((long)b * 1024) * 1536 + h * 64;

    for (int e = tid; e < 512; e += 256) {
        int r = e >> 6, d = e & 63;
        ql[r][d] = b2f_us(__builtin_bit_cast(unsigned short,
                       basep[(long)(q0 + r) * 1536 + d])) * 0.125f;
    }
    __syncthreads();
    // scores: each thread does 4 keys x 8 q-rows
    for (int t = tid; t < 1024; t += 256) {
        const bf16* kp = basep + 512 + (long)t * 1536;
        float acc[8] = {};
#pragma unroll
        for (int c = 0; c < 8; ++c) {
            ushort4 u0 = *(const ushort4*)(kp + c * 8);
            ushort4 u1 = *(const ushort4*)(kp + c * 8 + 4);
            float kf[8] = {b2f_us(u0.x), b2f_us(u0.y), b2f_us(u0.z), b2f_us(u0.w),
                           b2f_us(u1.x), b2f_us(u1.y), b2f_us(u1.z), b2f_us(u1.w)};
#pragma unroll
            for (int r = 0; r < 8; ++r)
#pragma unroll
                for (int j = 0; j < 8; ++j)
                    acc[r] = fmaf(kf[j], ql[r][c * 8 + j], acc[r]);
        }
#pragma unroll
        for (int r = 0; r < 8; ++r) sc[r][t] = acc[r];
    }
    __syncthreads();
    // softmax per row
    for (int r = 0; r < 8; ++r) {
        float m = -1e30f;
        for (int t = tid; t < 1024; t += 256) m = fmaxf(m, sc[r][t]);
#pragma unroll
        for (int off = 32; off; off >>= 1) m = fmaxf(m, __shfl_down(m, off));
        if ((tid & 63) == 0) red[tid >> 6] = m;
        __syncthreads();
        m = fmaxf(fmaxf(red[0], red[1]), fmaxf(red[2], red[3]));
        __syncthreads();
        float s = 0.f;
        for (int t = tid; t < 1024; t += 256) {
            float e = __expf(sc[r][t] - m);
            sc[r][t] = e;
            s += e;
        }
#pragma unroll
        for (int off = 32; off; off >>= 1) s += __shfl_down(s, off);
        if ((tid & 63) == 0) red[tid >> 6] = s;
        __syncthreads();
        float inv = 1.f / (red[0] + red[1] + red[2] + red[3]);
        __syncthreads();
        for (int t = tid; t < 1024; t += 256) sc[r][t] *= inv;
    }
    __syncthreads();
    // PV: V staged in LDS chunks of 64 keys
    const int d = tid & 63;
    const int r0 = (tid >> 6) * 2, r1 = r0 + 1;
    float a0 = 0.f, a1 = 0.f;
    for (int tc = 0; tc < 16; ++tc) {
#pragma unroll
        for (int it = 0; it < 4; ++it) {
            int e = tid + it * 256;
            int t = e >> 4, d2 = (e & 15) * 4;
            float4 v = ld4(basep + 1024 + (long)(tc * 64 + t) * 1536 + d2);
            vl[t][d2 + 0] = v.x;
            vl[t][d2 + 1] = v.y;
            vl[t][d2 + 2] = v.z;
            vl[t][d2 + 3] = v.w;
        }
        __syncthreads();
#pragma unroll
        for (int t = 0; t < 64; ++t) {
            float vv = vl[t][d];
            a0 = fmaf(sc[r0][tc * 64 + t], vv, a0);
            a1 = fmaf(sc[r1][tc * 64 + t], vv, a1);
        }
        __syncthreads();
    }
    bf16* op = o + ((long)b * 1024 + q0) * 512 + h * 64 + d;
    op[(long)r0 * 512] = __float2bfloat16(a0);
    op[(long)r1 * 512] = __float2bfloat16(a1);
}

// ---------------------------------------------------------------- launcher
extern "C" void kernel_launch(void* const* d_in, const int* in_sizes, int n_in,
                              void* d_out, int out_size, void* d_ws, size_t ws_size,
                              hipStream_t stream) {
    const float* x = (const float*)d_in[0];
    const float* gn_g = (const float*)d_in[1];
    const float* gn_b = (const float*)d_in[2];
    const float* w_cin = (const float*)d_in[3];
    const float* b_cin = (const float*)d_in[4];
    const float* ln1_g = (const float*)d_in[5];
    const float* ln1_b = (const float*)d_in[6];
    const float* qkv1w = (const float*)d_in[7];
    const float* out1_w = (const float*)d_in[8];
    const float* out1_b = (const float*)d_in[9];
    const float* ln2_g = (const float*)d_in[10];
    const float* ln2_b = (const float*)d_in[11];
    const float* qkv2w = (const float*)d_in[12];
    const float* out2_w = (const float*)d_in[13];
    const float* out2_b = (const float*)d_in[14];
    const float* ln3_g = (const float*)d_in[15];
    const float* ln3_b = (const float*)d_in[16];
    const float* g1_w = (const float*)d_in[17];
    const float* g1_b = (const float*)d_in[18];
    const float* g2_w = (const float*)d_in[19];
    const float* g2_b = (const float*)d_in[20];
    const float* w_cout = (const float*)d_in[21];
    const float* b_cout = (const float*)d_in[22];
    float* out = (float*)d_out;

    char* ws = (char*)d_ws;
    float* stats = (float*)ws;                      // 512 floats
    bf16* h = (bf16*)(ws + 4096);                   // (B,S,C)
    bf16* h2 = h + (size_t)8 * 1024 * 512;          // (B,S,C)
    bf16* lnb = h2 + (size_t)8 * 1024 * 512;        // (B,S,C)
    bf16* qkv = lnb + (size_t)8 * 1024 * 512;       // (B,S,3C)
    bf16* obuf = qkv + (size_t)8 * 1024 * 1536;     // (B,S,C)
    bf16* gg = qkv;  // (B,S,2048) reuses qkv+obuf region (exact fit)

    const long SC = 1024l * 512, S3C = 1024l * 1536, SG = 1024l * 2048, CS = 512l * 1024;

    gn_stats_k<<<256, 256, 0, stream>>>(x, stats);
    // conv_in: h[b,s,o] = sum_c W[o,c]*gn(x)[b,c,s] + b_cin[o]
    gemm_k<EPI_CIN, true, false, float, float, bf16, bf16>
        <<<dim3(8, 16, 8), 256, 0, stream>>>(
        x, w_cin, b_cin, nullptr, h, 1024, 512, 512,
        1, 1024, CS, 1, 512, 0, SC, 0, 0, stats, gn_g, gn_b);

    ln_k<<<8192, 256, 0, stream>>>(h, ln1_g, ln1_b, lnb);
    gemm_k<EPI_PLAIN, false, true, bf16, float, bf16, bf16>
        <<<dim3(24, 16, 8), 256, 0, stream>>>(
        lnb, qkv1w, nullptr, nullptr, qkv, 1024, 1536, 512,
        512, 1, SC, 1536, 1, 0, S3C, 0, 0, nullptr, nullptr, nullptr);
    attn_k<<<dim3(128, 8, 8), 256, 0, stream>>>(qkv, obuf);
    gemm_k<EPI_BIASRES, false, true, bf16, float, bf16, bf16>
        <<<dim3(8, 16, 8), 256, 0, stream>>>(
        obuf, out1_w, out1_b, h, h2, 1024, 512, 512,
        512, 1, SC, 512, 1, 0, SC, 512, SC, nullptr, nullptr, nullptr);

    ln_k<<<8192, 256, 0, stream>>>(h2, ln2_g, ln2_b, lnb);
    gemm_k<EPI_PLAIN, false, true, bf16, float, bf16, bf16>
        <<<dim3(24, 16, 8), 256, 0, stream>>>(
        lnb, qkv2w, nullptr, nullptr, qkv, 1024, 1536, 512,
        512, 1, SC, 1536, 1, 0, S3C, 0, 0, nullptr, nullptr, nullptr);
    attn_k<<<dim3(128, 8, 8), 256, 0, stream>>>(qkv, obuf);
    gemm_k<EPI_BIASRES, false, true, bf16, float, bf16, bf16>
        <<<dim3(8, 16, 8), 256, 0, stream>>>(
        obuf, out2_w, out2_b, h2, h, 1024, 512, 512,
        512, 1, SC, 512, 1, 0, SC, 512, SC, nullptr, nullptr, nullptr);

    ln_k<<<8192, 256, 0, stream>>>(h, ln3_g, ln3_b, lnb);
    gemm_geglu<<<dim3(32, 16, 8), 256, 0, stream>>>(lnb, g1_w, g1_b, gg);
    gemm_k<EPI_BIASRES, false, true, bf16, float, bf16, bf16>
        <<<dim3(8, 16, 8), 256, 0, stream>>>(
        gg, g2_w, g2_b, h, h2, 1024, 512, 2048,
        2048, 1, SG, 512, 1, 0, SC, 512, SC, nullptr, nullptr, nullptr);

    // conv_out: out[b,o,s] = sum_c W[o,c]*h2[b,s,c] + b_cout[o] + x[b,o,s]
    gemm_k<EPI_CONVOUT, false, false, float, bf16, float, float>
        <<<dim3(16, 8, 8), 256, 0, stream>>>(
        w_cout, h2, b_cout, x, out, 512, 1024, 512,
        512, 1, 0, 1, 512, SC, CS, 1024, CS, nullptr, nullptr, nullptr);
}

// Round 3
// 1451.018 us; speedup vs baseline: 3.7294x; 3.7294x over previous
//
#include <hip/hip_runtime.h>
#include <hip/hip_bf16.h>
#include <math.h>

typedef __hip_bfloat16 bf16;

typedef __bf16 bf16x8 __attribute__((ext_vector_type(8)));
typedef float f32x4 __attribute__((ext_vector_type(4)));
typedef short shortx8 __attribute__((ext_vector_type(8)));

__device__ __forceinline__ float b2f_us(unsigned short u) {
    unsigned int v = ((unsigned int)u) << 16;
    return __builtin_bit_cast(float, v);
}
__device__ __forceinline__ unsigned short f2b_us(float f) {
    return __builtin_bit_cast(unsigned short, __float2bfloat16(f));
}

__device__ __forceinline__ float4 ld4(const float* p) { return *(const float4*)p; }
__device__ __forceinline__ float4 ld4(const bf16* p) {
    ushort4 u = *(const ushort4*)p;
    return make_float4(b2f_us(u.x), b2f_us(u.y), b2f_us(u.z), b2f_us(u.w));
}
__device__ __forceinline__ void st4(float* p, float4 v) { *(float4*)p = v; }
__device__ __forceinline__ void st4(bf16* p, float4 v) {
    ushort4 o;
    o.x = f2b_us(v.x); o.y = f2b_us(v.y); o.z = f2b_us(v.z); o.w = f2b_us(v.w);
    *(ushort4*)p = o;
}

__device__ __forceinline__ bf16x8 ldfrag(const bf16* p) {
    return __builtin_bit_cast(bf16x8, *(const shortx8*)p);
}
__device__ __forceinline__ f32x4 mfma16(bf16x8 a, bf16x8 b, f32x4 c) {
    return __builtin_amdgcn_mfma_f32_16x16x32_bf16(a, b, c, 0, 0, 0);
}

// ---------------------------------------------------------------- GN stats (x is f32)
__global__ __launch_bounds__(256) void gn_stats_k(const float* __restrict__ x,
                                                  float* __restrict__ stats) {
    int bg = blockIdx.x;                 // b*32 + g
    long base = (long)bg * 16384;        // 16 ch * 1024 spatial, contiguous
    int tid = threadIdx.x;
    float s = 0.f, sq = 0.f;
    for (int it = 0; it < 16; ++it) {
        float4 v = *(const float4*)(x + base + (long)it * 1024 + tid * 4);
        s += v.x + v.y + v.z + v.w;
        sq += v.x * v.x + v.y * v.y + v.z * v.z + v.w * v.w;
    }
#pragma unroll
    for (int off = 32; off; off >>= 1) {
        s += __shfl_down(s, off);
        sq += __shfl_down(sq, off);
    }
    __shared__ float r0[4], r1[4];
    if ((tid & 63) == 0) { r0[tid >> 6] = s; r1[tid >> 6] = sq; }
    __syncthreads();
    if (tid == 0) {
        s = r0[0] + r0[1] + r0[2] + r0[3];
        sq = r1[0] + r1[1] + r1[2] + r1[3];
        float mu = s * (1.f / 16384.f);
        float var = sq * (1.f / 16384.f) - mu * mu;
        stats[bg] = mu;
        stats[256 + bg] = rsqrtf(var + 1e-6f);
    }
}

// ---------------------------------------------------------------- LayerNorm (ws bf16 -> ws bf16)
__global__ __launch_bounds__(256) void ln_k(const bf16* __restrict__ in,
                                            const float* __restrict__ g,
                                            const float* __restrict__ bvec,
                                            bf16* __restrict__ out) {
    long row = blockIdx.x;
    const bf16* p = in + row * 512;
    int tid = threadIdx.x;
    float v0 = b2f_us(__builtin_bit_cast(unsigned short, p[tid]));
    float v1 = b2f_us(__builtin_bit_cast(unsigned short, p[tid + 256]));
    float s = v0 + v1, sq = v0 * v0 + v1 * v1;
#pragma unroll
    for (int off = 32; off; off >>= 1) {
        s += __shfl_down(s, off);
        sq += __shfl_down(sq, off);
    }
    __shared__ float r0[4], r1[4];
    if ((tid & 63) == 0) { r0[tid >> 6] = s; r1[tid >> 6] = sq; }
    __syncthreads();
    s = r0[0] + r0[1] + r0[2] + r0[3];
    sq = r1[0] + r1[1] + r1[2] + r1[3];
    float mu = s * (1.f / 512.f);
    float var = sq * (1.f / 512.f) - mu * mu;
    float rs = rsqrtf(var + 1e-5f);
    out[row * 512 + tid] = __float2bfloat16((v0 - mu) * rs * g[tid] + bvec[tid]);
    out[row * 512 + tid + 256] =
        __float2bfloat16((v1 - mu) * rs * g[tid + 256] + bvec[tid + 256]);
}

// ---------------------------------------------------------------- GEMM (f32 VALU, 64x64 tile)
constexpr int EPI_CIN = 0;      // GN-normalize A on load, +bias[n]
constexpr int EPI_PLAIN = 1;    // no bias
constexpr int EPI_BIASRES = 2;  // +bias[n] +res[m][n]
constexpr int EPI_CONVOUT = 3;  // +bias[m] +res[m][n]

template <int EPI, bool A_MCONT, bool B_NCONT, typename TA, typename TB,
          typename TR, typename TC>
__global__ __launch_bounds__(256) void gemm_k(
    const TA* __restrict__ Ag, const TB* __restrict__ Bg,
    const float* __restrict__ bias, const TR* __restrict__ resg,
    TC* __restrict__ Cg, int M, int N, int K,
    long sAm, long sAk, long sAb,
    long sBk, long sBn, long sBb,
    long sCb, long sRm, long sRb,
    const float* __restrict__ gnstats,
    const float* __restrict__ gng, const float* __restrict__ gnb) {
    const int b = blockIdx.z;
    const int m0 = blockIdx.y * 64, n0 = blockIdx.x * 64;
    const TA* A = Ag + (long)b * sAb;
    const TB* B = Bg + (long)b * sBb;
    __shared__ float Al[16][68];
    __shared__ float Bl[16][68];
    const int tid = threadIdx.x;
    const int tx = tid & 15, ty = tid >> 4;
    float acc[16] = {};

    for (int k0 = 0; k0 < K; k0 += 16) {
        if (A_MCONT) {  // m contiguous in memory: vector-load along m
            int m4 = (tid & 15) * 4, k = tid >> 4;
            const TA* p = A + (long)(k0 + k) * sAk + (long)(m0 + m4) * sAm;
            float4 v = ld4(p);
            if (EPI == EPI_CIN) {
                int c = k0 + k;
                float mu = gnstats[b * 32 + (c >> 4)];
                float rs = gnstats[256 + b * 32 + (c >> 4)];
                float ga = gng[c] * rs;
                float be = gnb[c] - mu * ga;
                v.x = v.x * ga + be; v.y = v.y * ga + be;
                v.z = v.z * ga + be; v.w = v.w * ga + be;
            }
            *(float4*)&Al[k][m4] = v;
        } else {  // k contiguous: vector-load along k
            int k4 = (tid & 3) * 4, m = tid >> 2;
            const TA* p = A + (long)(m0 + m) * sAm + (long)(k0 + k4) * sAk;
            float4 v = ld4(p);
            Al[k4 + 0][m] = v.x;
            Al[k4 + 1][m] = v.y;
            Al[k4 + 2][m] = v.z;
            Al[k4 + 3][m] = v.w;
        }
        if (B_NCONT) {
            int n4 = (tid & 15) * 4, k = tid >> 4;
            const TB* p = B + (long)(k0 + k) * sBk + (long)(n0 + n4) * sBn;
            *(float4*)&Bl[k][n4] = ld4(p);
        } else {
            int k4 = (tid & 3) * 4, n = tid >> 2;
            const TB* p = B + (long)(n0 + n) * sBn + (long)(k0 + k4) * sBk;
            float4 v = ld4(p);
            Bl[k4 + 0][n] = v.x;
            Bl[k4 + 1][n] = v.y;
            Bl[k4 + 2][n] = v.z;
            Bl[k4 + 3][n] = v.w;
        }
        __syncthreads();
#pragma unroll
        for (int kk = 0; kk < 16; ++kk) {
            float4 a4 = *(const float4*)&Al[kk][ty * 4];
            float4 b4 = *(const float4*)&Bl[kk][tx * 4];
            float av[4] = {a4.x, a4.y, a4.z, a4.w};
            float bv[4] = {b4.x, b4.y, b4.z, b4.w};
#pragma unroll
            for (int i = 0; i < 4; ++i)
#pragma unroll
                for (int j = 0; j < 4; ++j)
                    acc[i * 4 + j] = fmaf(av[i], bv[j], acc[i * 4 + j]);
        }
        __syncthreads();
    }
#pragma unroll
    for (int i = 0; i < 4; ++i) {
        int row = m0 + ty * 4 + i;
        float vals[4];
#pragma unroll
        for (int j = 0; j < 4; ++j) vals[j] = acc[i * 4 + j];
        if (EPI == EPI_CIN || EPI == EPI_BIASRES) {
            float4 bi4 = *(const float4*)(bias + n0 + tx * 4);
            vals[0] += bi4.x; vals[1] += bi4.y;
            vals[2] += bi4.z; vals[3] += bi4.w;
        }
        if (EPI == EPI_CONVOUT) {
            float bm = bias[row];
            vals[0] += bm; vals[1] += bm; vals[2] += bm; vals[3] += bm;
        }
        if (EPI == EPI_BIASRES || EPI == EPI_CONVOUT) {
            float4 r4 = ld4(resg + (long)b * sRb + (long)row * sRm + n0 + tx * 4);
            vals[0] += r4.x; vals[1] += r4.y;
            vals[2] += r4.z; vals[3] += r4.w;
        }
        st4(Cg + (long)b * sCb + (long)row * N + n0 + tx * 4,
            make_float4(vals[0], vals[1], vals[2], vals[3]));
    }
}

// ---------------------------------------------------------------- GEGLU GEMM (g1 + gelu-gate)
__global__ __launch_bounds__(256) void gemm_geglu(const bf16* __restrict__ Ag,
                                                  const float* __restrict__ Bg,
                                                  const float* __restrict__ bias,
                                                  bf16* __restrict__ Cg) {
    const int b = blockIdx.z;
    const int n0 = blockIdx.x * 64, m0 = blockIdx.y * 64;
    const bf16* A = Ag + (long)b * 1024 * 512;
    __shared__ float Al[16][68], Bv[16][68], Bg2[16][68];
    const int tid = threadIdx.x, tx = tid & 15, ty = tid >> 4;
    float accv[16] = {}, accg[16] = {};
    for (int k0 = 0; k0 < 512; k0 += 16) {
        {
            int k4 = (tid & 3) * 4, m = tid >> 2;
            float4 v = ld4(A + (long)(m0 + m) * 512 + k0 + k4);
            Al[k4 + 0][m] = v.x;
            Al[k4 + 1][m] = v.y;
            Al[k4 + 2][m] = v.z;
            Al[k4 + 3][m] = v.w;
        }
        {
            int n4 = (tid & 15) * 4, k = tid >> 4;
            const float* p = Bg + (long)(k0 + k) * 4096 + n0 + n4;
            *(float4*)&Bv[k][n4] = *(const float4*)p;
            *(float4*)&Bg2[k][n4] = *(const float4*)(p + 2048);
        }
        __syncthreads();
#pragma unroll
        for (int kk = 0; kk < 16; ++kk) {
            float4 a4 = *(const float4*)&Al[kk][ty * 4];
            float4 v4 = *(const float4*)&Bv[kk][tx * 4];
            float4 g4 = *(const float4*)&Bg2[kk][tx * 4];
            float av[4] = {a4.x, a4.y, a4.z, a4.w};
            float bv[4] = {v4.x, v4.y, v4.z, v4.w};
            float bg[4] = {g4.x, g4.y, g4.z, g4.w};
#pragma unroll
            for (int i = 0; i < 4; ++i)
#pragma unroll
                for (int j = 0; j < 4; ++j) {
                    accv[i * 4 + j] = fmaf(av[i], bv[j], accv[i * 4 + j]);
                    accg[i * 4 + j] = fmaf(av[i], bg[j], accg[i * 4 + j]);
                }
        }
        __syncthreads();
    }
#pragma unroll
    for (int i = 0; i < 4; ++i) {
        int row = m0 + ty * 4 + i;
        ushort4 o4;
#pragma unroll
        for (int j = 0; j < 4; ++j) {
            int n = n0 + tx * 4 + j;
            float v = accv[i * 4 + j] + bias[n];
            float g = accg[i * 4 + j] + bias[2048 + n];
            float gl = 0.5f * g * (1.f + erff(g * 0.70710678118654752f));
            ((unsigned short*)&o4)[j] = f2b_us(v * gl);
        }
        *(ushort4*)(Cg + (long)b * 1024 * 2048 + (long)row * 2048 + n0 + tx * 4) = o4;
    }
}

// ---------------------------------------------------------------- V transpose: Vt[b][h][d][s]
__global__ __launch_bounds__(256) void vtrans_k(const bf16* __restrict__ qkv,
                                                bf16* __restrict__ vt) {
    const int bh = blockIdx.y;            // b*8+h
    const int b = bh >> 3, h = bh & 7;
    const int l = threadIdx.x & 63, w = threadIdx.x >> 6;
    const bf16* vsrc = qkv + (long)b * 1024 * 1536 + 1024 + h * 64 + l;
    bf16* vdst = vt + ((long)bh * 64 + l) * 1024;
    const int sbase = blockIdx.x * 256;   // grid.x = 4
    for (int ch = 0; ch < 8; ++ch) {
        int s0 = sbase + ch * 32 + w * 8;
        shortx8 tmp;
#pragma unroll
        for (int i = 0; i < 8; ++i)
            tmp[i] = __builtin_bit_cast(short, vsrc[(long)(s0 + i) * 1536]);
        *(shortx8*)(vdst + s0) = tmp;
    }
}

// ---------------------------------------------------------------- MFMA flash attention
// grid (16, H=8, B=8), 256 threads = 4 waves, each wave owns 16 q-rows.
__global__ __launch_bounds__(256) void attn_mfma_k(const bf16* __restrict__ qkv,
                                                   const bf16* __restrict__ vt,
                                                   bf16* __restrict__ o) {
    const int wave = threadIdx.x >> 6, lane = threadIdx.x & 63;
    const int lr = lane & 15, lg = lane >> 4;
    const int h = blockIdx.y, b = blockIdx.z;
    const int q0 = blockIdx.x * 64 + wave * 16;
    __shared__ bf16 plds[4][16][72];      // per-wave P tile, padded
    bf16* pl = &plds[wave][0][0];
    const bf16* qbase = qkv + (long)b * 1024 * 1536 + h * 64;
    const bf16* kbase = qbase + 512;
    const bf16* vbase = vt + ((long)(b * 8 + h) * 64) * 1024;

    // Q fragments (A-frag: row=lane&15, k=(lane>>4)*8+j), scaled by 1/8 (exact in bf16)
    bf16x8 qf[2];
    {
        const bf16* qp = qbase + (long)(q0 + lr) * 1536 + lg * 8;
#pragma unroll
        for (int c = 0; c < 2; ++c) {
            shortx8 raw = *(const shortx8*)(qp + c * 32);
            shortx8 sc;
#pragma unroll
            for (int j = 0; j < 8; ++j)
                sc[j] = __builtin_bit_cast(short,
                    f2b_us(b2f_us((unsigned short)raw[j]) * 0.125f));
            qf[c] = __builtin_bit_cast(bf16x8, sc);
        }
    }

    f32x4 zf = {0.f, 0.f, 0.f, 0.f};
    f32x4 of[4];
    of[0] = zf; of[1] = zf; of[2] = zf; of[3] = zf;
    float mrow[4] = {-1e30f, -1e30f, -1e30f, -1e30f};
    float lrowv[4] = {0.f, 0.f, 0.f, 0.f};

    for (int kv0 = 0; kv0 < 1024; kv0 += 64) {
        // ---- QK^T: 4 key-subtiles x (k=64 as 2 mfmas). K B-frag == K row fragment.
        f32x4 sf[4];
#pragma unroll
        for (int kt = 0; kt < 4; ++kt) {
            const bf16* kp = kbase + (long)(kv0 + kt * 16 + lr) * 1536 + lg * 8;
            f32x4 z = zf;
            z = mfma16(qf[0], ldfrag(kp), z);
            z = mfma16(qf[1], ldfrag(kp + 32), z);
            sf[kt] = z;
        }
        // ---- online softmax (rows live in 16-lane groups; reduce over lr)
        float mt[4];
#pragma unroll
        for (int r = 0; r < 4; ++r)
            mt[r] = fmaxf(fmaxf(sf[0][r], sf[1][r]), fmaxf(sf[2][r], sf[3][r]));
#pragma unroll
        for (int m = 1; m < 16; m <<= 1)
#pragma unroll
            for (int r = 0; r < 4; ++r)
                mt[r] = fmaxf(mt[r], __shfl_xor(mt[r], m));
        float al[4];
#pragma unroll
        for (int r = 0; r < 4; ++r) {
            float mn = fmaxf(mrow[r], mt[r]);
            al[r] = __expf(mrow[r] - mn);
            mrow[r] = mn;
        }
        float psum[4] = {0.f, 0.f, 0.f, 0.f};
#pragma unroll
        for (int kt = 0; kt < 4; ++kt)
#pragma unroll
            for (int r = 0; r < 4; ++r) {
                float p = __expf(sf[kt][r] - mrow[r]);
                psum[r] += p;
                pl[(lg * 4 + r) * 72 + kt * 16 + lr] = __float2bfloat16(p);
            }
#pragma unroll
        for (int m = 1; m < 16; m <<= 1)
#pragma unroll
            for (int r = 0; r < 4; ++r)
                psum[r] += __shfl_xor(psum[r], m);
#pragma unroll
        for (int r = 0; r < 4; ++r) lrowv[r] = lrowv[r] * al[r] + psum[r];
#pragma unroll
        for (int dt = 0; dt < 4; ++dt)
#pragma unroll
            for (int r = 0; r < 4; ++r) of[dt][r] *= al[r];
        // ---- PV: A-frag = P rows from LDS, B-frag = Vt rows (key-contiguous)
        bf16x8 pa0 = ldfrag(pl + lr * 72 + lg * 8);
        bf16x8 pa1 = ldfrag(pl + lr * 72 + 32 + lg * 8);
#pragma unroll
        for (int dt = 0; dt < 4; ++dt) {
            const bf16* vp = vbase + (long)(dt * 16 + lr) * 1024 + kv0 + lg * 8;
            of[dt] = mfma16(pa0, ldfrag(vp), of[dt]);
            of[dt] = mfma16(pa1, ldfrag(vp + 32), of[dt]);
        }
    }
    // ---- epilogue: O /= l, store (D-frag: row=(lane>>4)*4+r, col=lane&15)
    bf16* op = o + ((long)b * 1024 + q0 + lg * 4) * 512 + h * 64 + lr;
#pragma unroll
    for (int r = 0; r < 4; ++r) {
        float inv = 1.f / lrowv[r];
#pragma unroll
        for (int dt = 0; dt < 4; ++dt)
            op[(long)r * 512 + dt * 16] = __float2bfloat16(of[dt][r] * inv);
    }
}

// ---------------------------------------------------------------- launcher
extern "C" void kernel_launch(void* const* d_in, const int* in_sizes, int n_in,
                              void* d_out, int out_size, void* d_ws, size_t ws_size,
                              hipStream_t stream) {
    const float* x = (const float*)d_in[0];
    const float* gn_g = (const float*)d_in[1];
    const float* gn_b = (const float*)d_in[2];
    const float* w_cin = (const float*)d_in[3];
    const float* b_cin = (const float*)d_in[4];
    const float* ln1_g = (const float*)d_in[5];
    const float* ln1_b = (const float*)d_in[6];
    const float* qkv1w = (const float*)d_in[7];
    const float* out1_w = (const float*)d_in[8];
    const float* out1_b = (const float*)d_in[9];
    const float* ln2_g = (const float*)d_in[10];
    const float* ln2_b = (const float*)d_in[11];
    const float* qkv2w = (const float*)d_in[12];
    const float* out2_w = (const float*)d_in[13];
    const float* out2_b = (const float*)d_in[14];
    const float* ln3_g = (const float*)d_in[15];
    const float* ln3_b = (const float*)d_in[16];
    const float* g1_w = (const float*)d_in[17];
    const float* g1_b = (const float*)d_in[18];
    const float* g2_w = (const float*)d_in[19];
    const float* g2_b = (const float*)d_in[20];
    const float* w_cout = (const float*)d_in[21];
    const float* b_cout = (const float*)d_in[22];
    float* out = (float*)d_out;

    char* ws = (char*)d_ws;
    float* stats = (float*)ws;                      // 512 floats
    bf16* h = (bf16*)(ws + 4096);                   // (B,S,C)
    bf16* h2 = h + (size_t)8 * 1024 * 512;          // (B,S,C)
    bf16* lnb = h2 + (size_t)8 * 1024 * 512;        // (B,S,C) — also reused as Vt
    bf16* qkv = lnb + (size_t)8 * 1024 * 512;       // (B,S,3C)
    bf16* obuf = qkv + (size_t)8 * 1024 * 1536;     // (B,S,C)
    bf16* gg = qkv;   // (B,S,2048) reuses qkv+obuf region (exact fit)
    bf16* vt = lnb;   // (B,H,64,S) reuses lnb after qkv GEMM consumed it

    const long SC = 1024l * 512, S3C = 1024l * 1536, SG = 1024l * 2048, CS = 512l * 1024;

    gn_stats_k<<<256, 256, 0, stream>>>(x, stats);
    // conv_in: h[b,s,o] = sum_c W[o,c]*gn(x)[b,c,s] + b_cin[o]
    gemm_k<EPI_CIN, true, false, float, float, bf16, bf16>
        <<<dim3(8, 16, 8), 256, 0, stream>>>(
        x, w_cin, b_cin, nullptr, h, 1024, 512, 512,
        1, 1024, CS, 1, 512, 0, SC, 0, 0, stats, gn_g, gn_b);

    ln_k<<<8192, 256, 0, stream>>>(h, ln1_g, ln1_b, lnb);
    gemm_k<EPI_PLAIN, false, true, bf16, float, bf16, bf16>
        <<<dim3(24, 16, 8), 256, 0, stream>>>(
        lnb, qkv1w, nullptr, nullptr, qkv, 1024, 1536, 512,
        512, 1, SC, 1536, 1, 0, S3C, 0, 0, nullptr, nullptr, nullptr);
    vtrans_k<<<dim3(4, 64), 256, 0, stream>>>(qkv, vt);
    attn_mfma_k<<<dim3(16, 8, 8), 256, 0, stream>>>(qkv, vt, obuf);
    gemm_k<EPI_BIASRES, false, true, bf16, float, bf16, bf16>
        <<<dim3(8, 16, 8), 256, 0, stream>>>(
        obuf, out1_w, out1_b, h, h2, 1024, 512, 512,
        512, 1, SC, 512, 1, 0, SC, 512, SC, nullptr, nullptr, nullptr);

    ln_k<<<8192, 256, 0, stream>>>(h2, ln2_g, ln2_b, lnb);
    gemm_k<EPI_PLAIN, false, true, bf16, float, bf16, bf16>
        <<<dim3(24, 16, 8), 256, 0, stream>>>(
        lnb, qkv2w, nullptr, nullptr, qkv, 1024, 1536, 512,
        512, 1, SC, 1536, 1, 0, S3C, 0, 0, nullptr, nullptr, nullptr);
    vtrans_k<<<dim3(4, 64), 256, 0, stream>>>(qkv, vt);
    attn_mfma_k<<<dim3(16, 8, 8), 256, 0, stream>>>(qkv, vt, obuf);
    gemm_k<EPI_BIASRES, false, true, bf16, float, bf16, bf16>
        <<<dim3(8, 16, 8), 256, 0, stream>>>(
        obuf, out2_w, out2_b, h2, h, 1024, 512, 512,
        512, 1, SC, 512, 1, 0, SC, 512, SC, nullptr, nullptr, nullptr);

    ln_k<<<8192, 256, 0, stream>>>(h, ln3_g, ln3_b, lnb);
    gemm_geglu<<<dim3(32, 16, 8), 256, 0, stream>>>(lnb, g1_w, g1_b, gg);
    gemm_k<EPI_BIASRES, false, true, bf16, float, bf16, bf16>
        <<<dim3(8, 16, 8), 256, 0, stream>>>(
        gg, g2_w, g2_b, h, h2, 1024, 512, 2048,
        2048, 1, SG, 512, 1, 0, SC, 512, SC, nullptr, nullptr, nullptr);

    // conv_out: out[b,o,s] = sum_c W[o,c]*h2[b,s,c] + b_cout[o] + x[b,o,s]
    gemm_k<EPI_CONVOUT, false, false, float, bf16, float, float>
        <<<dim3(16, 8, 8), 256, 0, stream>>>(
        w_cout, h2, b_cout, x, out, 512, 1024, 512,
        512, 1, 0, 1, 512, SC, CS, 1024, CS, nullptr, nullptr, nullptr);
}

// Round 4
// 617.885 us; speedup vs baseline: 8.7580x; 2.3484x over previous
//
#include <hip/hip_runtime.h>
#include <hip/hip_bf16.h>
#include <math.h>

typedef __hip_bfloat16 bf16;

typedef __bf16 bf16x8 __attribute__((ext_vector_type(8)));
typedef float f32x4 __attribute__((ext_vector_type(4)));
typedef short shortx8 __attribute__((ext_vector_type(8)));

__device__ __forceinline__ float b2f_us(unsigned short u) {
    unsigned int v = ((unsigned int)u) << 16;
    return __builtin_bit_cast(float, v);
}
__device__ __forceinline__ unsigned short f2b_us(float f) {
    return __builtin_bit_cast(unsigned short, __float2bfloat16(f));
}
__device__ __forceinline__ float4 ld4(const float* p) { return *(const float4*)p; }
__device__ __forceinline__ float4 ld4(const bf16* p) {
    ushort4 u = *(const ushort4*)p;
    return make_float4(b2f_us(u.x), b2f_us(u.y), b2f_us(u.z), b2f_us(u.w));
}
__device__ __forceinline__ bf16x8 ldfrag(const bf16* p) {
    return __builtin_bit_cast(bf16x8, *(const shortx8*)p);
}
__device__ __forceinline__ f32x4 mfma16(bf16x8 a, bf16x8 b, f32x4 c) {
    return __builtin_amdgcn_mfma_f32_16x16x32_bf16(a, b, c, 0, 0, 0);
}
__device__ __forceinline__ void gload16(const bf16* g, bf16* l) {
    __builtin_amdgcn_global_load_lds(
        (const __attribute__((address_space(1))) void*)g,
        (__attribute__((address_space(3))) void*)l, 16, 0, 0);
}

// ---------------------------------------------------------------- batched weight convert
struct WJob { const float* src; bf16* dst; int R, C, tile0, trans; };
struct WJobs { WJob j[8]; };

__global__ __launch_bounds__(256) void wconv_all(WJobs jobs) {
    __shared__ float tl[32][33];
    int bid = blockIdx.x;
    int ji = 0;
#pragma unroll
    for (int i = 1; i < 8; ++i)
        if (bid >= jobs.j[i].tile0) ji = i;
    WJob jb = jobs.j[ji];
    int t = bid - jb.tile0;
    int tc = jb.C >> 5;
    int tr_ = t / tc, tcx = t - tr_ * tc;
    int r0 = tr_ * 32, c0 = tcx * 32;
    const int tx = threadIdx.x & 31, ty = threadIdx.x >> 5;
    if (jb.trans) {
#pragma unroll
        for (int i = 0; i < 4; ++i)
            tl[ty + i * 8][tx] = jb.src[(long)(r0 + ty + i * 8) * jb.C + c0 + tx];
        __syncthreads();
#pragma unroll
        for (int i = 0; i < 4; ++i)
            jb.dst[(long)(c0 + ty + i * 8) * jb.R + r0 + tx] =
                __float2bfloat16(tl[tx][ty + i * 8]);
    } else {
#pragma unroll
        for (int i = 0; i < 4; ++i) {
            long idx = (long)(r0 + ty + i * 8) * jb.C + c0 + tx;
            jb.dst[idx] = __float2bfloat16(jb.src[idx]);
        }
    }
}

// ---------------------------------------------------------------- GN stats
__global__ __launch_bounds__(256) void gn_stats_k(const float* __restrict__ x,
                                                  float* __restrict__ stats) {
    int bg = blockIdx.x;
    long base = (long)bg * 16384;
    int tid = threadIdx.x;
    float s = 0.f, sq = 0.f;
    for (int it = 0; it < 16; ++it) {
        float4 v = *(const float4*)(x + base + (long)it * 1024 + tid * 4);
        s += v.x + v.y + v.z + v.w;
        sq += v.x * v.x + v.y * v.y + v.z * v.z + v.w * v.w;
    }
#pragma unroll
    for (int off = 32; off; off >>= 1) {
        s += __shfl_down(s, off);
        sq += __shfl_down(sq, off);
    }
    __shared__ float r0[4], r1[4];
    if ((tid & 63) == 0) { r0[tid >> 6] = s; r1[tid >> 6] = sq; }
    __syncthreads();
    if (tid == 0) {
        s = r0[0] + r0[1] + r0[2] + r0[3];
        sq = r1[0] + r1[1] + r1[2] + r1[3];
        float mu = s * (1.f / 16384.f);
        float var = sq * (1.f / 16384.f) - mu * mu;
        stats[bg] = mu;
        stats[256 + bg] = rsqrtf(var + 1e-6f);
    }
}

// ---------------------------------------------------------------- GN + transpose + bf16: xt[b][s][c]
__global__ __launch_bounds__(256) void gnxt_k(const float* __restrict__ x,
                                              const float* __restrict__ stats,
                                              const float* __restrict__ gng,
                                              const float* __restrict__ gnb,
                                              bf16* __restrict__ xt) {
    const int b = blockIdx.z;
    const int c0 = blockIdx.y * 64, s0 = blockIdx.x * 64;
    __shared__ float t[64][65];
    const int tx = threadIdx.x & 15, ty = threadIdx.x >> 4;
#pragma unroll
    for (int i = 0; i < 4; ++i) {
        int c = c0 + ty + i * 16;
        float rs = stats[256 + b * 32 + (c >> 4)];
        float ga = gng[c] * rs;
        float be = gnb[c] - stats[b * 32 + (c >> 4)] * ga;
        float4 v = *(const float4*)(x + ((long)b * 512 + c) * 1024 + s0 + tx * 4);
        t[ty + i * 16][tx * 4 + 0] = v.x * ga + be;
        t[ty + i * 16][tx * 4 + 1] = v.y * ga + be;
        t[ty + i * 16][tx * 4 + 2] = v.z * ga + be;
        t[ty + i * 16][tx * 4 + 3] = v.w * ga + be;
    }
    __syncthreads();
#pragma unroll
    for (int i = 0; i < 4; ++i) {
        int s = s0 + ty + i * 16;
        ushort4 o;
        o.x = f2b_us(t[tx * 4 + 0][ty + i * 16]);
        o.y = f2b_us(t[tx * 4 + 1][ty + i * 16]);
        o.z = f2b_us(t[tx * 4 + 2][ty + i * 16]);
        o.w = f2b_us(t[tx * 4 + 3][ty + i * 16]);
        *(ushort4*)(xt + ((long)b * 1024 + s) * 512 + c0 + tx * 4) = o;
    }
}

// ---------------------------------------------------------------- LayerNorm
__global__ __launch_bounds__(256) void ln_k(const bf16* __restrict__ in,
                                            const float* __restrict__ g,
                                            const float* __restrict__ bvec,
                                            bf16* __restrict__ out) {
    long row = blockIdx.x;
    const bf16* p = in + row * 512;
    int tid = threadIdx.x;
    float v0 = b2f_us(__builtin_bit_cast(unsigned short, p[tid]));
    float v1 = b2f_us(__builtin_bit_cast(unsigned short, p[tid + 256]));
    float s = v0 + v1, sq = v0 * v0 + v1 * v1;
#pragma unroll
    for (int off = 32; off; off >>= 1) {
        s += __shfl_down(s, off);
        sq += __shfl_down(sq, off);
    }
    __shared__ float r0[4], r1[4];
    if ((tid & 63) == 0) { r0[tid >> 6] = s; r1[tid >> 6] = sq; }
    __syncthreads();
    s = r0[0] + r0[1] + r0[2] + r0[3];
    sq = r1[0] + r1[1] + r1[2] + r1[3];
    float mu = s * (1.f / 512.f);
    float var = sq * (1.f / 512.f) - mu * mu;
    float rs = rsqrtf(var + 1e-5f);
    out[row * 512 + tid] = __float2bfloat16((v0 - mu) * rs * g[tid] + bvec[tid]);
    out[row * 512 + tid + 256] =
        __float2bfloat16((v1 - mu) * rs * g[tid + 256] + bvec[tid + 256]);
}

// ---------------------------------------------------------------- MFMA GEMM 128x128, BK=64
// A (8192 x K) row-major lda=K; B (N x K) row-major ldb=K; C (8192 x N) ldc.
template <bool HASBIAS, bool HASRES>
__global__ __launch_bounds__(256, 2) void mm_k(
    const bf16* __restrict__ A, const bf16* __restrict__ Bw,
    const float* __restrict__ bias, const bf16* __restrict__ res,
    bf16* __restrict__ C, int lda, int ldb, int ldc, int NT) {
    __shared__ bf16 sA[2][8192];
    __shared__ bf16 sB[2][8192];
    const int lane = threadIdx.x & 63, wave = threadIdx.x >> 6;
    const int lr = lane & 15, lg = lane >> 4;
    const int wm = wave >> 1, wn = wave & 1;
    const int m0 = blockIdx.y * 128, n0 = blockIdx.x * 128;

    f32x4 acc[4][4];
#pragma unroll
    for (int i = 0; i < 4; ++i)
#pragma unroll
        for (int j = 0; j < 4; ++j) acc[i][j] = (f32x4){0.f, 0.f, 0.f, 0.f};

    auto stage = [&](int buf, int k0) {
#pragma unroll
        for (int t = 0; t < 4; ++t) {
            int st = wave * 4 + t;
            int sm = st & 7, sk = st >> 3;
            gload16(A + (long)(m0 + sm * 16 + lr) * lda + k0 + sk * 32 + lg * 8,
                    &sA[buf][st << 9]);
            gload16(Bw + (long)(n0 + sm * 16 + lr) * ldb + k0 + sk * 32 + lg * 8,
                    &sB[buf][st << 9]);
        }
    };
    auto compute = [&](int buf) {
#pragma unroll
        for (int sk = 0; sk < 2; ++sk) {
            bf16x8 af[4], bfr[4];
#pragma unroll
            for (int i = 0; i < 4; ++i)
                af[i] = ldfrag(&sA[buf][((sk * 8 + wm * 4 + i) << 9) + lane * 8]);
#pragma unroll
            for (int j = 0; j < 4; ++j)
                bfr[j] = ldfrag(&sB[buf][((sk * 8 + wn * 4 + j) << 9) + lane * 8]);
#pragma unroll
            for (int i = 0; i < 4; ++i)
#pragma unroll
                for (int j = 0; j < 4; ++j)
                    acc[i][j] = mfma16(af[i], bfr[j], acc[i][j]);
        }
    };

    stage(0, 0);
    asm volatile("s_waitcnt vmcnt(0)" ::: "memory");
    __syncthreads();
    int buf = 0;
    for (int t = 1; t < NT; ++t) {
        stage(buf ^ 1, t * 64);
        compute(buf);
        asm volatile("s_waitcnt vmcnt(0)" ::: "memory");
        __syncthreads();
        buf ^= 1;
    }
    compute(buf);

#pragma unroll
    for (int i = 0; i < 4; ++i) {
        int row = m0 + wm * 64 + i * 16 + lg * 4;
#pragma unroll
        for (int j = 0; j < 4; ++j) {
            int col = n0 + wn * 64 + j * 16 + lr;
            float bv = HASBIAS ? bias[col] : 0.f;
#pragma unroll
            for (int r = 0; r < 4; ++r) {
                float v = acc[i][j][r] + bv;
                if (HASRES)
                    v += b2f_us(__builtin_bit_cast(unsigned short,
                             res[(long)(row + r) * ldc + col]));
                C[(long)(row + r) * ldc + col] = __float2bfloat16(v);
            }
        }
    }
}

// ---------------------------------------------------------------- MFMA GEGLU GEMM (val||gate)
__global__ __launch_bounds__(256, 2) void mm_geglu_k(
    const bf16* __restrict__ A, const bf16* __restrict__ Bv,
    const bf16* __restrict__ Bg, const float* __restrict__ bias,
    bf16* __restrict__ C, int NT) {
    __shared__ bf16 sA[2][8192];
    __shared__ bf16 sB[2][8192];
    const int lane = threadIdx.x & 63, wave = threadIdx.x >> 6;
    const int lr = lane & 15, lg = lane >> 4;
    const int wm = wave >> 1, wn = wave & 1;
    const int m0 = blockIdx.y * 128, n0 = blockIdx.x * 64;

    f32x4 accv[4][2], accg[4][2];
#pragma unroll
    for (int i = 0; i < 4; ++i)
#pragma unroll
        for (int j = 0; j < 2; ++j) {
            accv[i][j] = (f32x4){0.f, 0.f, 0.f, 0.f};
            accg[i][j] = (f32x4){0.f, 0.f, 0.f, 0.f};
        }

    auto stage = [&](int buf, int k0) {
#pragma unroll
        for (int t = 0; t < 4; ++t) {
            int st = wave * 4 + t;
            int sm = st & 7, skA = st >> 3;
            gload16(A + (long)(m0 + sm * 16 + lr) * 512 + k0 + skA * 32 + lg * 8,
                    &sA[buf][st << 9]);
            int skB = st >> 3, half = (st >> 2) & 1, sn = st & 3;
            const bf16* bsrc = half ? Bg : Bv;
            gload16(bsrc + (long)(n0 + sn * 16 + lr) * 512 + k0 + skB * 32 + lg * 8,
                    &sB[buf][st << 9]);
        }
    };
    auto compute = [&](int buf) {
#pragma unroll
        for (int sk = 0; sk < 2; ++sk) {
            bf16x8 af[4], bv_[2], bg_[2];
#pragma unroll
            for (int i = 0; i < 4; ++i)
                af[i] = ldfrag(&sA[buf][((sk * 8 + wm * 4 + i) << 9) + lane * 8]);
#pragma unroll
            for (int j = 0; j < 2; ++j) {
                bv_[j] = ldfrag(&sB[buf][((sk * 8 + wn * 2 + j) << 9) + lane * 8]);
                bg_[j] = ldfrag(&sB[buf][((sk * 8 + 4 + wn * 2 + j) << 9) + lane * 8]);
            }
#pragma unroll
            for (int i = 0; i < 4; ++i)
#pragma unroll
                for (int j = 0; j < 2; ++j) {
                    accv[i][j] = mfma16(af[i], bv_[j], accv[i][j]);
                    accg[i][j] = mfma16(af[i], bg_[j], accg[i][j]);
                }
        }
    };

    stage(0, 0);
    asm volatile("s_waitcnt vmcnt(0)" ::: "memory");
    __syncthreads();
    int buf = 0;
    for (int t = 1; t < NT; ++t) {
        stage(buf ^ 1, t * 64);
        compute(buf);
        asm volatile("s_waitcnt vmcnt(0)" ::: "memory");
        __syncthreads();
        buf ^= 1;
    }
    compute(buf);

#pragma unroll
    for (int i = 0; i < 4; ++i) {
        int row = m0 + wm * 64 + i * 16 + lg * 4;
#pragma unroll
        for (int j = 0; j < 2; ++j) {
            int col = n0 + (wn * 2 + j) * 16 + lr;
            float bv = bias[col], bg2 = bias[2048 + col];
#pragma unroll
            for (int r = 0; r < 4; ++r) {
                float v = accv[i][j][r] + bv;
                float g = accg[i][j][r] + bg2;
                float gl = 0.5f * g * (1.f + erff(g * 0.70710678118654752f));
                C[(long)(row + r) * 2048 + col] = __float2bfloat16(v * gl);
            }
        }
    }
}

// ---------------------------------------------------------------- V transpose: Vt[b][h][d][s]
__global__ __launch_bounds__(256) void vtrans_k(const bf16* __restrict__ qkv,
                                                bf16* __restrict__ vt) {
    const int bh = blockIdx.y;
    const int b = bh >> 3, h = bh & 7;
    const int l = threadIdx.x & 63, w = threadIdx.x >> 6;
    const bf16* vsrc = qkv + (long)b * 1024 * 1536 + 1024 + h * 64 + l;
    bf16* vdst = vt + ((long)bh * 64 + l) * 1024;
    const int sbase = blockIdx.x * 256;
    for (int ch = 0; ch < 8; ++ch) {
        int s0 = sbase + ch * 32 + w * 8;
        shortx8 tmp;
#pragma unroll
        for (int i = 0; i < 8; ++i)
            tmp[i] = __builtin_bit_cast(short, vsrc[(long)(s0 + i) * 1536]);
        *(shortx8*)(vdst + s0) = tmp;
    }
}

// ---------------------------------------------------------------- MFMA flash attention
__global__ __launch_bounds__(256) void attn_mfma_k(const bf16* __restrict__ qkv,
                                                   const bf16* __restrict__ vt,
                                                   bf16* __restrict__ o) {
    const int wave = threadIdx.x >> 6, lane = threadIdx.x & 63;
    const int lr = lane & 15, lg = lane >> 4;
    const int h = blockIdx.y, b = blockIdx.z;
    const int q0 = blockIdx.x * 64 + wave * 16;
    __shared__ bf16 plds[4][16][72];
    bf16* pl = &plds[wave][0][0];
    const bf16* qbase = qkv + (long)b * 1024 * 1536 + h * 64;
    const bf16* kbase = qbase + 512;
    const bf16* vbase = vt + ((long)(b * 8 + h) * 64) * 1024;

    bf16x8 qf[2];
    {
        const bf16* qp = qbase + (long)(q0 + lr) * 1536 + lg * 8;
#pragma unroll
        for (int c = 0; c < 2; ++c) {
            shortx8 raw = *(const shortx8*)(qp + c * 32);
            shortx8 sc;
#pragma unroll
            for (int j = 0; j < 8; ++j)
                sc[j] = __builtin_bit_cast(short,
                    f2b_us(b2f_us((unsigned short)raw[j]) * 0.125f));
            qf[c] = __builtin_bit_cast(bf16x8, sc);
        }
    }

    f32x4 zf = {0.f, 0.f, 0.f, 0.f};
    f32x4 of[4];
    of[0] = zf; of[1] = zf; of[2] = zf; of[3] = zf;
    float mrow[4] = {-1e30f, -1e30f, -1e30f, -1e30f};
    float lrowv[4] = {0.f, 0.f, 0.f, 0.f};

    for (int kv0 = 0; kv0 < 1024; kv0 += 64) {
        f32x4 sf[4];
#pragma unroll
        for (int kt = 0; kt < 4; ++kt) {
            const bf16* kp = kbase + (long)(kv0 + kt * 16 + lr) * 1536 + lg * 8;
            f32x4 z = zf;
            z = mfma16(qf[0], ldfrag(kp), z);
            z = mfma16(qf[1], ldfrag(kp + 32), z);
            sf[kt] = z;
        }
        float mt[4];
#pragma unroll
        for (int r = 0; r < 4; ++r)
            mt[r] = fmaxf(fmaxf(sf[0][r], sf[1][r]), fmaxf(sf[2][r], sf[3][r]));
#pragma unroll
        for (int m = 1; m < 16; m <<= 1)
#pragma unroll
            for (int r = 0; r < 4; ++r)
                mt[r] = fmaxf(mt[r], __shfl_xor(mt[r], m));
        float al[4];
#pragma unroll
        for (int r = 0; r < 4; ++r) {
            float mn = fmaxf(mrow[r], mt[r]);
            al[r] = __expf(mrow[r] - mn);
            mrow[r] = mn;
        }
        float psum[4] = {0.f, 0.f, 0.f, 0.f};
#pragma unroll
        for (int kt = 0; kt < 4; ++kt)
#pragma unroll
            for (int r = 0; r < 4; ++r) {
                float p = __expf(sf[kt][r] - mrow[r]);
                psum[r] += p;
                pl[(lg * 4 + r) * 72 + kt * 16 + lr] = __float2bfloat16(p);
            }
#pragma unroll
        for (int m = 1; m < 16; m <<= 1)
#pragma unroll
            for (int r = 0; r < 4; ++r)
                psum[r] += __shfl_xor(psum[r], m);
#pragma unroll
        for (int r = 0; r < 4; ++r) lrowv[r] = lrowv[r] * al[r] + psum[r];
#pragma unroll
        for (int dt = 0; dt < 4; ++dt)
#pragma unroll
            for (int r = 0; r < 4; ++r) of[dt][r] *= al[r];
        bf16x8 pa0 = ldfrag(pl + lr * 72 + lg * 8);
        bf16x8 pa1 = ldfrag(pl + lr * 72 + 32 + lg * 8);
#pragma unroll
        for (int dt = 0; dt < 4; ++dt) {
            const bf16* vp = vbase + (long)(dt * 16 + lr) * 1024 + kv0 + lg * 8;
            of[dt] = mfma16(pa0, ldfrag(vp), of[dt]);
            of[dt] = mfma16(pa1, ldfrag(vp + 32), of[dt]);
        }
    }
    bf16* op = o + ((long)b * 1024 + q0 + lg * 4) * 512 + h * 64 + lr;
#pragma unroll
    for (int r = 0; r < 4; ++r) {
        float inv = 1.f / lrowv[r];
#pragma unroll
        for (int dt = 0; dt < 4; ++dt)
            op[(long)r * 512 + dt * 16] = __float2bfloat16(of[dt][r] * inv);
    }
}

// ---------------------------------------------------------------- conv_out epilogue: transpose + bias + residual
__global__ __launch_bounds__(256) void outepi_k(const bf16* __restrict__ tmp,
                                                const float* __restrict__ bcout,
                                                const float* __restrict__ x,
                                                float* __restrict__ out) {
    const int b = blockIdx.z;
    const int o0 = blockIdx.y * 64, s0 = blockIdx.x * 64;
    __shared__ float t[64][65];
    const int tx = threadIdx.x & 15, ty = threadIdx.x >> 4;
#pragma unroll
    for (int i = 0; i < 4; ++i) {
        int s = s0 + ty + i * 16;
        float4 v = ld4(tmp + ((long)b * 1024 + s) * 512 + o0 + tx * 4);
        t[ty + i * 16][tx * 4 + 0] = v.x;
        t[ty + i * 16][tx * 4 + 1] = v.y;
        t[ty + i * 16][tx * 4 + 2] = v.z;
        t[ty + i * 16][tx * 4 + 3] = v.w;
    }
    __syncthreads();
#pragma unroll
    for (int i = 0; i < 4; ++i) {
        int o = o0 + ty + i * 16;
        long idx = ((long)b * 512 + o) * 1024 + s0 + tx * 4;
        float4 xr = *(const float4*)(x + idx);
        float bc = bcout[o];
        float4 w;
        w.x = t[tx * 4 + 0][ty + i * 16] + bc + xr.x;
        w.y = t[tx * 4 + 1][ty + i * 16] + bc + xr.y;
        w.z = t[tx * 4 + 2][ty + i * 16] + bc + xr.z;
        w.w = t[tx * 4 + 3][ty + i * 16] + bc + xr.w;
        *(float4*)(out + idx) = w;
    }
}

// ---------------------------------------------------------------- launcher
extern "C" void kernel_launch(void* const* d_in, const int* in_sizes, int n_in,
                              void* d_out, int out_size, void* d_ws, size_t ws_size,
                              hipStream_t stream) {
    const float* x = (const float*)d_in[0];
    const float* gn_g = (const float*)d_in[1];
    const float* gn_b = (const float*)d_in[2];
    const float* w_cin = (const float*)d_in[3];
    const float* b_cin = (const float*)d_in[4];
    const float* ln1_g = (const float*)d_in[5];
    const float* ln1_b = (const float*)d_in[6];
    const float* qkv1w = (const float*)d_in[7];
    const float* out1_w = (const float*)d_in[8];
    const float* out1_b = (const float*)d_in[9];
    const float* ln2_g = (const float*)d_in[10];
    const float* ln2_b = (const float*)d_in[11];
    const float* qkv2w = (const float*)d_in[12];
    const float* out2_w = (const float*)d_in[13];
    const float* out2_b = (const float*)d_in[14];
    const float* ln3_g = (const float*)d_in[15];
    const float* ln3_b = (const float*)d_in[16];
    const float* g1_w = (const float*)d_in[17];
    const float* g1_b = (const float*)d_in[18];
    const float* g2_w = (const float*)d_in[19];
    const float* g2_b = (const float*)d_in[20];
    const float* w_cout = (const float*)d_in[21];
    const float* b_cout = (const float*)d_in[22];
    float* out = (float*)d_out;

    char* ws = (char*)d_ws;
    float* stats = (float*)ws;
    bf16* wq1 = (bf16*)(ws + 4096);          // (1536,512)
    bf16* wo1 = wq1 + 1536 * 512;            // (512,512)
    bf16* wq2 = wo1 + 512 * 512;             // (1536,512)
    bf16* wo2 = wq2 + 1536 * 512;            // (512,512)
    bf16* wg1 = wo2 + 512 * 512;             // (4096,512)
    bf16* wg2 = wg1 + 4096 * 512;            // (512,2048)
    bf16* wci = wg2 + 512 * 2048;            // (512,512)
    bf16* wco = wci + 512 * 512;             // (512,512)
    bf16* h = wco + 512 * 512;               // (8192,512)
    bf16* h2 = h + (size_t)8192 * 512;
    bf16* lnb = h2 + (size_t)8192 * 512;     // also xt / vt / tmp
    bf16* qkv = lnb + (size_t)8192 * 512;    // (8192,1536)
    bf16* obuf = qkv + (size_t)8192 * 1536;  // (8192,512)
    bf16* gg = qkv;                          // (8192,2048) reuses qkv+obuf
    bf16* vt = lnb;

    WJobs jobs;
    jobs.j[0] = {qkv1w, wq1, 512, 1536, 0, 1};
    jobs.j[1] = {out1_w, wo1, 512, 512, 768, 1};
    jobs.j[2] = {qkv2w, wq2, 512, 1536, 1024, 1};
    jobs.j[3] = {out2_w, wo2, 512, 512, 1792, 1};
    jobs.j[4] = {g1_w, wg1, 512, 4096, 2048, 1};
    jobs.j[5] = {g2_w, wg2, 2048, 512, 4096, 1};
    jobs.j[6] = {w_cin, wci, 512, 512, 5120, 0};
    jobs.j[7] = {w_cout, wco, 512, 512, 5376, 0};
    wconv_all<<<5632, 256, 0, stream>>>(jobs);

    gn_stats_k<<<256, 256, 0, stream>>>(x, stats);
    gnxt_k<<<dim3(16, 8, 8), 256, 0, stream>>>(x, stats, gn_g, gn_b, lnb);
    // conv_in
    mm_k<true, false><<<dim3(4, 64), 256, 0, stream>>>(
        lnb, wci, b_cin, nullptr, h, 512, 512, 512, 8);

    ln_k<<<8192, 256, 0, stream>>>(h, ln1_g, ln1_b, lnb);
    mm_k<false, false><<<dim3(12, 64), 256, 0, stream>>>(
        lnb, wq1, nullptr, nullptr, qkv, 512, 512, 1536, 8);
    vtrans_k<<<dim3(4, 64), 256, 0, stream>>>(qkv, vt);
    attn_mfma_k<<<dim3(16, 8, 8), 256, 0, stream>>>(qkv, vt, obuf);
    mm_k<true, true><<<dim3(4, 64), 256, 0, stream>>>(
        obuf, wo1, out1_b, h, h2, 512, 512, 512, 8);

    ln_k<<<8192, 256, 0, stream>>>(h2, ln2_g, ln2_b, lnb);
    mm_k<false, false><<<dim3(12, 64), 256, 0, stream>>>(
        lnb, wq2, nullptr, nullptr, qkv, 512, 512, 1536, 8);
    vtrans_k<<<dim3(4, 64), 256, 0, stream>>>(qkv, vt);
    attn_mfma_k<<<dim3(16, 8, 8), 256, 0, stream>>>(qkv, vt, obuf);
    mm_k<true, true><<<dim3(4, 64), 256, 0, stream>>>(
        obuf, wo2, out2_b, h2, h, 512, 512, 512, 8);

    ln_k<<<8192, 256, 0, stream>>>(h, ln3_g, ln3_b, lnb);
    mm_geglu_k<<<dim3(32, 64), 256, 0, stream>>>(
        lnb, wg1, wg1 + (size_t)2048 * 512, g1_b, gg, 8);
    mm_k<true, true><<<dim3(4, 64), 256, 0, stream>>>(
        gg, wg2, g2_b, h, h2, 2048, 2048, 512, 32);

    // conv_out: tmp = h2 @ w_cout^T  (w_cout rows are [o][c] = [n][k])
    mm_k<false, false><<<dim3(4, 64), 256, 0, stream>>>(
        h2, wco, nullptr, nullptr, lnb, 512, 512, 512, 8);
    outepi_k<<<dim3(16, 8, 8), 256, 0, stream>>>(lnb, b_cout, x, out);
}

// Round 5
// 438.551 us; speedup vs baseline: 12.3393x; 1.4089x over previous
//
#include <hip/hip_runtime.h>
#include <hip/hip_bf16.h>
#include <math.h>

typedef __hip_bfloat16 bf16;

typedef __bf16 bf16x8 __attribute__((ext_vector_type(8)));
typedef float f32x4 __attribute__((ext_vector_type(4)));
typedef short shortx8 __attribute__((ext_vector_type(8)));

__device__ __forceinline__ float b2f_us(unsigned short u) {
    unsigned int v = ((unsigned int)u) << 16;
    return __builtin_bit_cast(float, v);
}
__device__ __forceinline__ unsigned short f2b_us(float f) {
    return __builtin_bit_cast(unsigned short, __float2bfloat16(f));
}
__device__ __forceinline__ float4 ld4(const float* p) { return *(const float4*)p; }
__device__ __forceinline__ float4 ld4(const bf16* p) {
    ushort4 u = *(const ushort4*)p;
    return make_float4(b2f_us(u.x), b2f_us(u.y), b2f_us(u.z), b2f_us(u.w));
}
__device__ __forceinline__ bf16x8 ldfrag(const bf16* p) {
    return __builtin_bit_cast(bf16x8, *(const shortx8*)p);
}
__device__ __forceinline__ f32x4 mfma16(bf16x8 a, bf16x8 b, f32x4 c) {
    return __builtin_amdgcn_mfma_f32_16x16x32_bf16(a, b, c, 0, 0, 0);
}
__device__ __forceinline__ void gload16(const bf16* g, bf16* l) {
    __builtin_amdgcn_global_load_lds(
        (const __attribute__((address_space(1))) void*)g,
        (__attribute__((address_space(3))) void*)l, 16, 0, 0);
}

// ---------------------------------------------------------------- batched weight convert
struct WJob { const float* src; bf16* dst; int R, C, tile0, trans; };
struct WJobs { WJob j[8]; };

__global__ __launch_bounds__(256) void wconv_all(WJobs jobs) {
    __shared__ float tl[32][33];
    int bid = blockIdx.x;
    int ji = 0;
#pragma unroll
    for (int i = 1; i < 8; ++i)
        if (bid >= jobs.j[i].tile0) ji = i;
    WJob jb = jobs.j[ji];
    int t = bid - jb.tile0;
    int tc = jb.C >> 5;
    int tr_ = t / tc, tcx = t - tr_ * tc;
    int r0 = tr_ * 32, c0 = tcx * 32;
    const int tx = threadIdx.x & 31, ty = threadIdx.x >> 5;
    if (jb.trans) {
#pragma unroll
        for (int i = 0; i < 4; ++i)
            tl[ty + i * 8][tx] = jb.src[(long)(r0 + ty + i * 8) * jb.C + c0 + tx];
        __syncthreads();
#pragma unroll
        for (int i = 0; i < 4; ++i)
            jb.dst[(long)(c0 + ty + i * 8) * jb.R + r0 + tx] =
                __float2bfloat16(tl[tx][ty + i * 8]);
    } else {
#pragma unroll
        for (int i = 0; i < 4; ++i) {
            long idx = (long)(r0 + ty + i * 8) * jb.C + c0 + tx;
            jb.dst[idx] = __float2bfloat16(jb.src[idx]);
        }
    }
}

// ---------------------------------------------------------------- GN stats
__global__ __launch_bounds__(256) void gn_stats_k(const float* __restrict__ x,
                                                  float* __restrict__ stats) {
    int bg = blockIdx.x;
    long base = (long)bg * 16384;
    int tid = threadIdx.x;
    float s = 0.f, sq = 0.f;
    for (int it = 0; it < 16; ++it) {
        float4 v = *(const float4*)(x + base + (long)it * 1024 + tid * 4);
        s += v.x + v.y + v.z + v.w;
        sq += v.x * v.x + v.y * v.y + v.z * v.z + v.w * v.w;
    }
#pragma unroll
    for (int off = 32; off; off >>= 1) {
        s += __shfl_down(s, off);
        sq += __shfl_down(sq, off);
    }
    __shared__ float r0[4], r1[4];
    if ((tid & 63) == 0) { r0[tid >> 6] = s; r1[tid >> 6] = sq; }
    __syncthreads();
    if (tid == 0) {
        s = r0[0] + r0[1] + r0[2] + r0[3];
        sq = r1[0] + r1[1] + r1[2] + r1[3];
        float mu = s * (1.f / 16384.f);
        float var = sq * (1.f / 16384.f) - mu * mu;
        stats[bg] = mu;
        stats[256 + bg] = rsqrtf(var + 1e-6f);
    }
}

// ---------------------------------------------------------------- GN + transpose + bf16
__global__ __launch_bounds__(256) void gnxt_k(const float* __restrict__ x,
                                              const float* __restrict__ stats,
                                              const float* __restrict__ gng,
                                              const float* __restrict__ gnb,
                                              bf16* __restrict__ xt) {
    const int b = blockIdx.z;
    const int c0 = blockIdx.y * 64, s0 = blockIdx.x * 64;
    __shared__ float t[64][65];
    const int tx = threadIdx.x & 15, ty = threadIdx.x >> 4;
#pragma unroll
    for (int i = 0; i < 4; ++i) {
        int c = c0 + ty + i * 16;
        float rs = stats[256 + b * 32 + (c >> 4)];
        float ga = gng[c] * rs;
        float be = gnb[c] - stats[b * 32 + (c >> 4)] * ga;
        float4 v = *(const float4*)(x + ((long)b * 512 + c) * 1024 + s0 + tx * 4);
        t[ty + i * 16][tx * 4 + 0] = v.x * ga + be;
        t[ty + i * 16][tx * 4 + 1] = v.y * ga + be;
        t[ty + i * 16][tx * 4 + 2] = v.z * ga + be;
        t[ty + i * 16][tx * 4 + 3] = v.w * ga + be;
    }
    __syncthreads();
#pragma unroll
    for (int i = 0; i < 4; ++i) {
        int s = s0 + ty + i * 16;
        ushort4 o;
        o.x = f2b_us(t[tx * 4 + 0][ty + i * 16]);
        o.y = f2b_us(t[tx * 4 + 1][ty + i * 16]);
        o.z = f2b_us(t[tx * 4 + 2][ty + i * 16]);
        o.w = f2b_us(t[tx * 4 + 3][ty + i * 16]);
        *(ushort4*)(xt + ((long)b * 1024 + s) * 512 + c0 + tx * 4) = o;
    }
}

// ---------------------------------------------------------------- LayerNorm
__global__ __launch_bounds__(256) void ln_k(const bf16* __restrict__ in,
                                            const float* __restrict__ g,
                                            const float* __restrict__ bvec,
                                            bf16* __restrict__ out) {
    long row = blockIdx.x;
    const bf16* p = in + row * 512;
    int tid = threadIdx.x;
    float v0 = b2f_us(__builtin_bit_cast(unsigned short, p[tid]));
    float v1 = b2f_us(__builtin_bit_cast(unsigned short, p[tid + 256]));
    float s = v0 + v1, sq = v0 * v0 + v1 * v1;
#pragma unroll
    for (int off = 32; off; off >>= 1) {
        s += __shfl_down(s, off);
        sq += __shfl_down(sq, off);
    }
    __shared__ float r0[4], r1[4];
    if ((tid & 63) == 0) { r0[tid >> 6] = s; r1[tid >> 6] = sq; }
    __syncthreads();
    s = r0[0] + r0[1] + r0[2] + r0[3];
    sq = r1[0] + r1[1] + r1[2] + r1[3];
    float mu = s * (1.f / 512.f);
    float var = sq * (1.f / 512.f) - mu * mu;
    float rs = rsqrtf(var + 1e-5f);
    out[row * 512 + tid] = __float2bfloat16((v0 - mu) * rs * g[tid] + bvec[tid]);
    out[row * 512 + tid + 256] =
        __float2bfloat16((v1 - mu) * rs * g[tid + 256] + bvec[tid + 256]);
}

// ---------------------------------------------------------------- MFMA GEMM 128x128, BK=32, 3-buf pipeline
template <bool HASBIAS, bool HASRES>
__global__ __launch_bounds__(256, 2) void mm128_k(
    const bf16* __restrict__ A, const bf16* __restrict__ Bw,
    const float* __restrict__ bias, const bf16* __restrict__ res,
    bf16* __restrict__ C, int lda, int ldb, int ldc, int NT) {
    __shared__ bf16 sA[3][4096];
    __shared__ bf16 sB[3][4096];
    const int lane = threadIdx.x & 63, wave = threadIdx.x >> 6;
    const int lr = lane & 15, lg = lane >> 4;
    const int wm = wave >> 1, wn = wave & 1;
    const int m0 = blockIdx.y * 128, n0 = blockIdx.x * 128;

    f32x4 acc[4][4];
#pragma unroll
    for (int i = 0; i < 4; ++i)
#pragma unroll
        for (int j = 0; j < 4; ++j) acc[i][j] = (f32x4){0.f, 0.f, 0.f, 0.f};

    auto stage = [&](int buf, int k0) {
#pragma unroll
        for (int t2 = 0; t2 < 2; ++t2) {
            int sm = wave * 2 + t2;
            gload16(A + (long)(m0 + sm * 16 + lr) * lda + k0 + lg * 8,
                    &sA[buf][sm << 9]);
            gload16(Bw + (long)(n0 + sm * 16 + lr) * ldb + k0 + lg * 8,
                    &sB[buf][sm << 9]);
        }
    };
    auto compute = [&](int buf) {
        bf16x8 af[4], bfr[4];
#pragma unroll
        for (int i = 0; i < 4; ++i)
            af[i] = ldfrag(&sA[buf][((wm * 4 + i) << 9) + lane * 8]);
#pragma unroll
        for (int j = 0; j < 4; ++j)
            bfr[j] = ldfrag(&sB[buf][((wn * 4 + j) << 9) + lane * 8]);
#pragma unroll
        for (int i = 0; i < 4; ++i)
#pragma unroll
            for (int j = 0; j < 4; ++j)
                acc[i][j] = mfma16(af[i], bfr[j], acc[i][j]);
    };

    stage(0, 0);
    stage(1, 32);
    int bs = 2, br = 0;
    for (int t = 0; t < NT - 1; ++t) {
        asm volatile("s_waitcnt vmcnt(4) lgkmcnt(0)" ::: "memory");
        __builtin_amdgcn_s_barrier();
        if (t < NT - 2) { stage(bs, (t + 2) * 32); bs = bs == 2 ? 0 : bs + 1; }
        compute(br); br = br == 2 ? 0 : br + 1;
    }
    asm volatile("s_waitcnt vmcnt(0) lgkmcnt(0)" ::: "memory");
    __builtin_amdgcn_s_barrier();
    compute(br);

#pragma unroll
    for (int i = 0; i < 4; ++i) {
        int row = m0 + wm * 64 + i * 16 + lg * 4;
#pragma unroll
        for (int j = 0; j < 4; ++j) {
            int col = n0 + wn * 64 + j * 16 + lr;
            float bv = HASBIAS ? bias[col] : 0.f;
#pragma unroll
            for (int r = 0; r < 4; ++r) {
                float v = acc[i][j][r] + bv;
                if (HASRES)
                    v += b2f_us(__builtin_bit_cast(unsigned short,
                             res[(long)(row + r) * ldc + col]));
                C[(long)(row + r) * ldc + col] = __float2bfloat16(v);
            }
        }
    }
}

// ---------------------------------------------------------------- MFMA GEMM 64x128 (for N=512 GEMMs)
template <bool HASBIAS, bool HASRES>
__global__ __launch_bounds__(256, 2) void mm64_k(
    const bf16* __restrict__ A, const bf16* __restrict__ Bw,
    const float* __restrict__ bias, const bf16* __restrict__ res,
    bf16* __restrict__ C, int lda, int ldb, int ldc, int NT) {
    __shared__ bf16 sA[3][2048];
    __shared__ bf16 sB[3][4096];
    const int lane = threadIdx.x & 63, wave = threadIdx.x >> 6;
    const int lr = lane & 15, lg = lane >> 4;
    const int wm = wave >> 1, wn = wave & 1;
    const int m0 = blockIdx.y * 64, n0 = blockIdx.x * 128;

    f32x4 acc[2][4];
#pragma unroll
    for (int i = 0; i < 2; ++i)
#pragma unroll
        for (int j = 0; j < 4; ++j) acc[i][j] = (f32x4){0.f, 0.f, 0.f, 0.f};

    auto stage = [&](int buf, int k0) {
        gload16(A + (long)(m0 + wave * 16 + lr) * lda + k0 + lg * 8,
                &sA[buf][wave << 9]);
#pragma unroll
        for (int t2 = 0; t2 < 2; ++t2) {
            int sn = wave * 2 + t2;
            gload16(Bw + (long)(n0 + sn * 16 + lr) * ldb + k0 + lg * 8,
                    &sB[buf][sn << 9]);
        }
    };
    auto compute = [&](int buf) {
        bf16x8 af[2], bfr[4];
#pragma unroll
        for (int i = 0; i < 2; ++i)
            af[i] = ldfrag(&sA[buf][((wm * 2 + i) << 9) + lane * 8]);
#pragma unroll
        for (int j = 0; j < 4; ++j)
            bfr[j] = ldfrag(&sB[buf][((wn * 4 + j) << 9) + lane * 8]);
#pragma unroll
        for (int i = 0; i < 2; ++i)
#pragma unroll
            for (int j = 0; j < 4; ++j)
                acc[i][j] = mfma16(af[i], bfr[j], acc[i][j]);
    };

    stage(0, 0);
    stage(1, 32);
    int bs = 2, br = 0;
    for (int t = 0; t < NT - 1; ++t) {
        asm volatile("s_waitcnt vmcnt(3) lgkmcnt(0)" ::: "memory");
        __builtin_amdgcn_s_barrier();
        if (t < NT - 2) { stage(bs, (t + 2) * 32); bs = bs == 2 ? 0 : bs + 1; }
        compute(br); br = br == 2 ? 0 : br + 1;
    }
    asm volatile("s_waitcnt vmcnt(0) lgkmcnt(0)" ::: "memory");
    __builtin_amdgcn_s_barrier();
    compute(br);

#pragma unroll
    for (int i = 0; i < 2; ++i) {
        int row = m0 + wm * 32 + i * 16 + lg * 4;
#pragma unroll
        for (int j = 0; j < 4; ++j) {
            int col = n0 + wn * 64 + j * 16 + lr;
            float bv = HASBIAS ? bias[col] : 0.f;
#pragma unroll
            for (int r = 0; r < 4; ++r) {
                float v = acc[i][j][r] + bv;
                if (HASRES)
                    v += b2f_us(__builtin_bit_cast(unsigned short,
                             res[(long)(row + r) * ldc + col]));
                C[(long)(row + r) * ldc + col] = __float2bfloat16(v);
            }
        }
    }
}

// ---------------------------------------------------------------- MFMA GEGLU GEMM
__global__ __launch_bounds__(256, 2) void mm_geglu_k(
    const bf16* __restrict__ A, const bf16* __restrict__ Bv,
    const bf16* __restrict__ Bg, const float* __restrict__ bias,
    bf16* __restrict__ C, int NT) {
    __shared__ bf16 sA[3][4096];
    __shared__ bf16 sB[3][4096];
    const int lane = threadIdx.x & 63, wave = threadIdx.x >> 6;
    const int lr = lane & 15, lg = lane >> 4;
    const int wm = wave >> 1, wn = wave & 1;
    const int m0 = blockIdx.y * 128, n0 = blockIdx.x * 64;

    f32x4 accv[4][2], accg[4][2];
#pragma unroll
    for (int i = 0; i < 4; ++i)
#pragma unroll
        for (int j = 0; j < 2; ++j) {
            accv[i][j] = (f32x4){0.f, 0.f, 0.f, 0.f};
            accg[i][j] = (f32x4){0.f, 0.f, 0.f, 0.f};
        }

    auto stage = [&](int buf, int k0) {
#pragma unroll
        for (int t2 = 0; t2 < 2; ++t2) {
            int sm = wave * 2 + t2;
            gload16(A + (long)(m0 + sm * 16 + lr) * 512 + k0 + lg * 8,
                    &sA[buf][sm << 9]);
            const bf16* bsrc = (sm < 4) ? Bv : Bg;
            int sn = sm & 3;
            gload16(bsrc + (long)(n0 + sn * 16 + lr) * 512 + k0 + lg * 8,
                    &sB[buf][sm << 9]);
        }
    };
    auto compute = [&](int buf) {
        bf16x8 af[4], bv_[2], bg_[2];
#pragma unroll
        for (int i = 0; i < 4; ++i)
            af[i] = ldfrag(&sA[buf][((wm * 4 + i) << 9) + lane * 8]);
#pragma unroll
        for (int j = 0; j < 2; ++j) {
            bv_[j] = ldfrag(&sB[buf][((wn * 2 + j) << 9) + lane * 8]);
            bg_[j] = ldfrag(&sB[buf][((4 + wn * 2 + j) << 9) + lane * 8]);
        }
#pragma unroll
        for (int i = 0; i < 4; ++i)
#pragma unroll
            for (int j = 0; j < 2; ++j) {
                accv[i][j] = mfma16(af[i], bv_[j], accv[i][j]);
                accg[i][j] = mfma16(af[i], bg_[j], accg[i][j]);
            }
    };

    stage(0, 0);
    stage(1, 32);
    int bs = 2, br = 0;
    for (int t = 0; t < NT - 1; ++t) {
        asm volatile("s_waitcnt vmcnt(4) lgkmcnt(0)" ::: "memory");
        __builtin_amdgcn_s_barrier();
        if (t < NT - 2) { stage(bs, (t + 2) * 32); bs = bs == 2 ? 0 : bs + 1; }
        compute(br); br = br == 2 ? 0 : br + 1;
    }
    asm volatile("s_waitcnt vmcnt(0) lgkmcnt(0)" ::: "memory");
    __builtin_amdgcn_s_barrier();
    compute(br);

#pragma unroll
    for (int i = 0; i < 4; ++i) {
        int row = m0 + wm * 64 + i * 16 + lg * 4;
#pragma unroll
        for (int j = 0; j < 2; ++j) {
            int col = n0 + (wn * 2 + j) * 16 + lr;
            float bv = bias[col], bg2 = bias[2048 + col];
#pragma unroll
            for (int r = 0; r < 4; ++r) {
                float v = accv[i][j][r] + bv;
                float g = accg[i][j][r] + bg2;
                float gl = 0.5f * g * (1.f + erff(g * 0.70710678118654752f));
                C[(long)(row + r) * 2048 + col] = __float2bfloat16(v * gl);
            }
        }
    }
}

// ---------------------------------------------------------------- V transpose: Vt[b][h][d][s]
__global__ __launch_bounds__(256) void vtrans_k(const bf16* __restrict__ qkv,
                                                bf16* __restrict__ vt) {
    const int bh = blockIdx.y;
    const int b = bh >> 3, h = bh & 7;
    const int l = threadIdx.x & 63, w = threadIdx.x >> 6;
    const bf16* vsrc = qkv + (long)b * 1024 * 1536 + 1024 + h * 64 + l;
    bf16* vdst = vt + ((long)bh * 64 + l) * 1024;
    const int sbase = blockIdx.x * 256;
    for (int ch = 0; ch < 8; ++ch) {
        int s0 = sbase + ch * 32 + w * 8;
        shortx8 tmp;
#pragma unroll
        for (int i = 0; i < 8; ++i)
            tmp[i] = __builtin_bit_cast(short, vsrc[(long)(s0 + i) * 1536]);
        *(shortx8*)(vdst + s0) = tmp;
    }
}

// ---------------------------------------------------------------- MFMA flash attention, LDS-staged K/V
// grid (8, 8, 8); 4 waves x 32 q-rows = 128 q-rows per block.
__global__ __launch_bounds__(256) void attn_mfma_k(const bf16* __restrict__ qkv,
                                                   const bf16* __restrict__ vt,
                                                   bf16* __restrict__ o) {
    const int wave = threadIdx.x >> 6, lane = threadIdx.x & 63;
    const int lr = lane & 15, lg = lane >> 4;
    const int h = blockIdx.y, b = blockIdx.z;
    const int q0 = blockIdx.x * 128 + wave * 32;
    __shared__ bf16 sKV[3][8192];      // 8 K subtiles + 8 V subtiles, frag-linear
    __shared__ bf16 plds[4][16][72];   // per-wave P tile
    bf16* pl = &plds[wave][0][0];
    const bf16* qbase = qkv + (long)b * 1024 * 1536 + h * 64;
    const bf16* kbase = qbase + 512;
    const bf16* vbase = vt + ((long)(b * 8 + h) * 64) * 1024;

    // Q fragments, 2 row-sets of 16, scaled by 1/8 (exact in bf16)
    bf16x8 qf[2][2];
#pragma unroll
    for (int s = 0; s < 2; ++s) {
        const bf16* qp = qbase + (long)(q0 + s * 16 + lr) * 1536 + lg * 8;
#pragma unroll
        for (int c = 0; c < 2; ++c) {
            shortx8 raw = *(const shortx8*)(qp + c * 32);
            shortx8 sc;
#pragma unroll
            for (int j = 0; j < 8; ++j)
                sc[j] = __builtin_bit_cast(short,
                    f2b_us(b2f_us((unsigned short)raw[j]) * 0.125f));
            qf[s][c] = __builtin_bit_cast(bf16x8, sc);
        }
    }

    f32x4 of[2][4];
    float mrow[2][4], lrow[2][4];
#pragma unroll
    for (int s = 0; s < 2; ++s)
#pragma unroll
        for (int r = 0; r < 4; ++r) {
            of[s][r] = (f32x4){0.f, 0.f, 0.f, 0.f};
            mrow[s][r] = -1e30f;
            lrow[s][r] = 0.f;
        }

    auto stageKV = [&](int buf, int kv0) {
#pragma unroll
        for (int t2 = 0; t2 < 4; ++t2) {
            int st = wave * 4 + t2;
            const bf16* src;
            if (st < 8)
                src = kbase + (long)(kv0 + (st >> 1) * 16 + lr) * 1536 +
                      (st & 1) * 32 + lg * 8;
            else
                src = vbase + (long)(((st - 8) >> 1) * 16 + lr) * 1024 + kv0 +
                      (st & 1) * 32 + lg * 8;
            gload16(src, &sKV[buf][st << 9]);
        }
    };
    auto computeKV = [&](int buf) {
        const bf16* base = &sKV[buf][0];
        f32x4 sf[2][4];
#pragma unroll
        for (int kt = 0; kt < 4; ++kt) {
            bf16x8 k0f = ldfrag(base + (kt * 2) * 512 + lane * 8);
            bf16x8 k1f = ldfrag(base + (kt * 2 + 1) * 512 + lane * 8);
#pragma unroll
            for (int s = 0; s < 2; ++s) {
                f32x4 z = {0.f, 0.f, 0.f, 0.f};
                z = mfma16(qf[s][0], k0f, z);
                z = mfma16(qf[s][1], k1f, z);
                sf[s][kt] = z;
            }
        }
        bf16x8 pa[2][2];
#pragma unroll
        for (int s = 0; s < 2; ++s) {
            float mt[4];
#pragma unroll
            for (int r = 0; r < 4; ++r)
                mt[r] = fmaxf(fmaxf(sf[s][0][r], sf[s][1][r]),
                              fmaxf(sf[s][2][r], sf[s][3][r]));
#pragma unroll
            for (int m = 1; m < 16; m <<= 1)
#pragma unroll
                for (int r = 0; r < 4; ++r)
                    mt[r] = fmaxf(mt[r], __shfl_xor(mt[r], m));
            float al[4];
#pragma unroll
            for (int r = 0; r < 4; ++r) {
                float mn = fmaxf(mrow[s][r], mt[r]);
                al[r] = __expf(mrow[s][r] - mn);
                mrow[s][r] = mn;
            }
            float psum[4] = {0.f, 0.f, 0.f, 0.f};
#pragma unroll
            for (int kt = 0; kt < 4; ++kt)
#pragma unroll
                for (int r = 0; r < 4; ++r) {
                    float p = __expf(sf[s][kt][r] - mrow[s][r]);
                    psum[r] += p;
                    pl[(lg * 4 + r) * 72 + kt * 16 + lr] = __float2bfloat16(p);
                }
#pragma unroll
            for (int m = 1; m < 16; m <<= 1)
#pragma unroll
                for (int r = 0; r < 4; ++r)
                    psum[r] += __shfl_xor(psum[r], m);
#pragma unroll
            for (int r = 0; r < 4; ++r)
                lrow[s][r] = lrow[s][r] * al[r] + psum[r];
#pragma unroll
            for (int dt = 0; dt < 4; ++dt)
#pragma unroll
                for (int r = 0; r < 4; ++r) of[s][dt][r] *= al[r];
            pa[s][0] = ldfrag(pl + lr * 72 + lg * 8);
            pa[s][1] = ldfrag(pl + lr * 72 + 32 + lg * 8);
        }
#pragma unroll
        for (int dt = 0; dt < 4; ++dt) {
            bf16x8 v0f = ldfrag(base + (8 + dt * 2) * 512 + lane * 8);
            bf16x8 v1f = ldfrag(base + (8 + dt * 2 + 1) * 512 + lane * 8);
#pragma unroll
            for (int s = 0; s < 2; ++s) {
                of[s][dt] = mfma16(pa[s][0], v0f, of[s][dt]);
                of[s][dt] = mfma16(pa[s][1], v1f, of[s][dt]);
            }
        }
    };

    stageKV(0, 0);
    stageKV(1, 64);
    int bs = 2, br = 0;
    for (int t = 0; t < 15; ++t) {
        asm volatile("s_waitcnt vmcnt(4) lgkmcnt(0)" ::: "memory");
        __builtin_amdgcn_s_barrier();
        if (t < 14) { stageKV(bs, (t + 2) * 64); bs = bs == 2 ? 0 : bs + 1; }
        computeKV(br); br = br == 2 ? 0 : br + 1;
    }
    asm volatile("s_waitcnt vmcnt(0) lgkmcnt(0)" ::: "memory");
    __builtin_amdgcn_s_barrier();
    computeKV(br);

#pragma unroll
    for (int s = 0; s < 2; ++s) {
        bf16* op = o + ((long)b * 1024 + q0 + s * 16 + lg * 4) * 512 + h * 64 + lr;
#pragma unroll
        for (int r = 0; r < 4; ++r) {
            float inv = 1.f / lrow[s][r];
#pragma unroll
            for (int dt = 0; dt < 4; ++dt)
                op[(long)r * 512 + dt * 16] = __float2bfloat16(of[s][dt][r] * inv);
        }
    }
}

// ---------------------------------------------------------------- conv_out epilogue
__global__ __launch_bounds__(256) void outepi_k(const bf16* __restrict__ tmp,
                                                const float* __restrict__ bcout,
                                                const float* __restrict__ x,
                                                float* __restrict__ out) {
    const int b = blockIdx.z;
    const int o0 = blockIdx.y * 64, s0 = blockIdx.x * 64;
    __shared__ float t[64][65];
    const int tx = threadIdx.x & 15, ty = threadIdx.x >> 4;
#pragma unroll
    for (int i = 0; i < 4; ++i) {
        int s = s0 + ty + i * 16;
        float4 v = ld4(tmp + ((long)b * 1024 + s) * 512 + o0 + tx * 4);
        t[ty + i * 16][tx * 4 + 0] = v.x;
        t[ty + i * 16][tx * 4 + 1] = v.y;
        t[ty + i * 16][tx * 4 + 2] = v.z;
        t[ty + i * 16][tx * 4 + 3] = v.w;
    }
    __syncthreads();
#pragma unroll
    for (int i = 0; i < 4; ++i) {
        int o = o0 + ty + i * 16;
        long idx = ((long)b * 512 + o) * 1024 + s0 + tx * 4;
        float4 xr = *(const float4*)(x + idx);
        float bc = bcout[o];
        float4 w;
        w.x = t[tx * 4 + 0][ty + i * 16] + bc + xr.x;
        w.y = t[tx * 4 + 1][ty + i * 16] + bc + xr.y;
        w.z = t[tx * 4 + 2][ty + i * 16] + bc + xr.z;
        w.w = t[tx * 4 + 3][ty + i * 16] + bc + xr.w;
        *(float4*)(out + idx) = w;
    }
}

// ---------------------------------------------------------------- launcher
extern "C" void kernel_launch(void* const* d_in, const int* in_sizes, int n_in,
                              void* d_out, int out_size, void* d_ws, size_t ws_size,
                              hipStream_t stream) {
    const float* x = (const float*)d_in[0];
    const float* gn_g = (const float*)d_in[1];
    const float* gn_b = (const float*)d_in[2];
    const float* w_cin = (const float*)d_in[3];
    const float* b_cin = (const float*)d_in[4];
    const float* ln1_g = (const float*)d_in[5];
    const float* ln1_b = (const float*)d_in[6];
    const float* qkv1w = (const float*)d_in[7];
    const float* out1_w = (const float*)d_in[8];
    const float* out1_b = (const float*)d_in[9];
    const float* ln2_g = (const float*)d_in[10];
    const float* ln2_b = (const float*)d_in[11];
    const float* qkv2w = (const float*)d_in[12];
    const float* out2_w = (const float*)d_in[13];
    const float* out2_b = (const float*)d_in[14];
    const float* ln3_g = (const float*)d_in[15];
    const float* ln3_b = (const float*)d_in[16];
    const float* g1_w = (const float*)d_in[17];
    const float* g1_b = (const float*)d_in[18];
    const float* g2_w = (const float*)d_in[19];
    const float* g2_b = (const float*)d_in[20];
    const float* w_cout = (const float*)d_in[21];
    const float* b_cout = (const float*)d_in[22];
    float* out = (float*)d_out;

    char* ws = (char*)d_ws;
    float* stats = (float*)ws;
    bf16* wq1 = (bf16*)(ws + 4096);          // (1536,512)
    bf16* wo1 = wq1 + 1536 * 512;            // (512,512)
    bf16* wq2 = wo1 + 512 * 512;             // (1536,512)
    bf16* wo2 = wq2 + 1536 * 512;            // (512,512)
    bf16* wg1 = wo2 + 512 * 512;             // (4096,512)
    bf16* wg2 = wg1 + 4096 * 512;            // (512,2048)
    bf16* wci = wg2 + 512 * 2048;            // (512,512)
    bf16* wco = wci + 512 * 512;             // (512,512)
    bf16* h = wco + 512 * 512;               // (8192,512)
    bf16* h2 = h + (size_t)8192 * 512;
    bf16* lnb = h2 + (size_t)8192 * 512;     // also xt / vt / tmp
    bf16* qkv = lnb + (size_t)8192 * 512;    // (8192,1536)
    bf16* obuf = qkv + (size_t)8192 * 1536;  // (8192,512)
    bf16* gg = qkv;                          // (8192,2048) reuses qkv+obuf
    bf16* vt = lnb;

    WJobs jobs;
    jobs.j[0] = {qkv1w, wq1, 512, 1536, 0, 1};
    jobs.j[1] = {out1_w, wo1, 512, 512, 768, 1};
    jobs.j[2] = {qkv2w, wq2, 512, 1536, 1024, 1};
    jobs.j[3] = {out2_w, wo2, 512, 512, 1792, 1};
    jobs.j[4] = {g1_w, wg1, 512, 4096, 2048, 1};
    jobs.j[5] = {g2_w, wg2, 2048, 512, 4096, 1};
    jobs.j[6] = {w_cin, wci, 512, 512, 5120, 0};
    jobs.j[7] = {w_cout, wco, 512, 512, 5376, 0};
    wconv_all<<<5632, 256, 0, stream>>>(jobs);

    gn_stats_k<<<256, 256, 0, stream>>>(x, stats);
    gnxt_k<<<dim3(16, 8, 8), 256, 0, stream>>>(x, stats, gn_g, gn_b, lnb);
    // conv_in
    mm64_k<true, false><<<dim3(4, 128), 256, 0, stream>>>(
        lnb, wci, b_cin, nullptr, h, 512, 512, 512, 16);

    ln_k<<<8192, 256, 0, stream>>>(h, ln1_g, ln1_b, lnb);
    mm128_k<false, false><<<dim3(12, 64), 256, 0, stream>>>(
        lnb, wq1, nullptr, nullptr, qkv, 512, 512, 1536, 16);
    vtrans_k<<<dim3(4, 64), 256, 0, stream>>>(qkv, vt);
    attn_mfma_k<<<dim3(8, 8, 8), 256, 0, stream>>>(qkv, vt, obuf);
    mm64_k<true, true><<<dim3(4, 128), 256, 0, stream>>>(
        obuf, wo1, out1_b, h, h2, 512, 512, 512, 16);

    ln_k<<<8192, 256, 0, stream>>>(h2, ln2_g, ln2_b, lnb);
    mm128_k<false, false><<<dim3(12, 64), 256, 0, stream>>>(
        lnb, wq2, nullptr, nullptr, qkv, 512, 512, 1536, 16);
    vtrans_k<<<dim3(4, 64), 256, 0, stream>>>(qkv, vt);
    attn_mfma_k<<<dim3(8, 8, 8), 256, 0, stream>>>(qkv, vt, obuf);
    mm64_k<true, true><<<dim3(4, 128), 256, 0, stream>>>(
        obuf, wo2, out2_b, h2, h, 512, 512, 512, 16);

    ln_k<<<8192, 256, 0, stream>>>(h, ln3_g, ln3_b, lnb);
    mm_geglu_k<<<dim3(32, 64), 256, 0, stream>>>(
        lnb, wg1, wg1 + (size_t)2048 * 512, g1_b, gg, 16);
    mm64_k<true, true><<<dim3(4, 128), 256, 0, stream>>>(
        gg, wg2, g2_b, h, h2, 2048, 2048, 512, 64);

    // conv_out: tmp = h2 @ w_cout^T
    mm64_k<false, false><<<dim3(4, 128), 256, 0, stream>>>(
        h2, wco, nullptr, nullptr, lnb, 512, 512, 512, 16);
    outepi_k<<<dim3(16, 8, 8), 256, 0, stream>>>(lnb, b_cout, x, out);
}

// Round 6
// 436.211 us; speedup vs baseline: 12.4055x; 1.0054x over previous
//
#include <hip/hip_runtime.h>
#include <hip/hip_bf16.h>
#include <math.h>

typedef __hip_bfloat16 bf16;

typedef __bf16 bf16x8 __attribute__((ext_vector_type(8)));
typedef float f32x4 __attribute__((ext_vector_type(4)));
typedef short shortx8 __attribute__((ext_vector_type(8)));

__device__ __forceinline__ float b2f_us(unsigned short u) {
    unsigned int v = ((unsigned int)u) << 16;
    return __builtin_bit_cast(float, v);
}
__device__ __forceinline__ unsigned short f2b_us(float f) {
    return __builtin_bit_cast(unsigned short, __float2bfloat16(f));
}
__device__ __forceinline__ float4 ld4(const float* p) { return *(const float4*)p; }
__device__ __forceinline__ float4 ld4(const bf16* p) {
    ushort4 u = *(const ushort4*)p;
    return make_float4(b2f_us(u.x), b2f_us(u.y), b2f_us(u.z), b2f_us(u.w));
}
__device__ __forceinline__ bf16x8 ldfrag(const bf16* p) {
    return __builtin_bit_cast(bf16x8, *(const shortx8*)p);
}
__device__ __forceinline__ f32x4 mfma16(bf16x8 a, bf16x8 b, f32x4 c) {
    return __builtin_amdgcn_mfma_f32_16x16x32_bf16(a, b, c, 0, 0, 0);
}
__device__ __forceinline__ void gload16(const bf16* g, bf16* l) {
    __builtin_amdgcn_global_load_lds(
        (const __attribute__((address_space(1))) void*)g,
        (__attribute__((address_space(3))) void*)l, 16, 0, 0);
}

// ---------------------------------------------------------------- batched weight convert
struct WJob { const float* src; bf16* dst; int R, C, tile0, trans; };
struct WJobs { WJob j[8]; };

__global__ __launch_bounds__(256) void wconv_all(WJobs jobs) {
    __shared__ float tl[32][33];
    int bid = blockIdx.x;
    int ji = 0;
#pragma unroll
    for (int i = 1; i < 8; ++i)
        if (bid >= jobs.j[i].tile0) ji = i;
    WJob jb = jobs.j[ji];
    int t = bid - jb.tile0;
    int tc = jb.C >> 5;
    int tr_ = t / tc, tcx = t - tr_ * tc;
    int r0 = tr_ * 32, c0 = tcx * 32;
    const int tx = threadIdx.x & 31, ty = threadIdx.x >> 5;
    if (jb.trans) {
#pragma unroll
        for (int i = 0; i < 4; ++i)
            tl[ty + i * 8][tx] = jb.src[(long)(r0 + ty + i * 8) * jb.C + c0 + tx];
        __syncthreads();
#pragma unroll
        for (int i = 0; i < 4; ++i)
            jb.dst[(long)(c0 + ty + i * 8) * jb.R + r0 + tx] =
                __float2bfloat16(tl[tx][ty + i * 8]);
    } else {
#pragma unroll
        for (int i = 0; i < 4; ++i) {
            long idx = (long)(r0 + ty + i * 8) * jb.C + c0 + tx;
            jb.dst[idx] = __float2bfloat16(jb.src[idx]);
        }
    }
}

// ---------------------------------------------------------------- GN stats
__global__ __launch_bounds__(256) void gn_stats_k(const float* __restrict__ x,
                                                  float* __restrict__ stats) {
    int bg = blockIdx.x;
    long base = (long)bg * 16384;
    int tid = threadIdx.x;
    float s = 0.f, sq = 0.f;
    for (int it = 0; it < 16; ++it) {
        float4 v = *(const float4*)(x + base + (long)it * 1024 + tid * 4);
        s += v.x + v.y + v.z + v.w;
        sq += v.x * v.x + v.y * v.y + v.z * v.z + v.w * v.w;
    }
#pragma unroll
    for (int off = 32; off; off >>= 1) {
        s += __shfl_down(s, off);
        sq += __shfl_down(sq, off);
    }
    __shared__ float r0[4], r1[4];
    if ((tid & 63) == 0) { r0[tid >> 6] = s; r1[tid >> 6] = sq; }
    __syncthreads();
    if (tid == 0) {
        s = r0[0] + r0[1] + r0[2] + r0[3];
        sq = r1[0] + r1[1] + r1[2] + r1[3];
        float mu = s * (1.f / 16384.f);
        float var = sq * (1.f / 16384.f) - mu * mu;
        stats[bg] = mu;
        stats[256 + bg] = rsqrtf(var + 1e-6f);
    }
}

// ---------------------------------------------------------------- GN + transpose + bf16
__global__ __launch_bounds__(256) void gnxt_k(const float* __restrict__ x,
                                              const float* __restrict__ stats,
                                              const float* __restrict__ gng,
                                              const float* __restrict__ gnb,
                                              bf16* __restrict__ xt) {
    const int b = blockIdx.z;
    const int c0 = blockIdx.y * 64, s0 = blockIdx.x * 64;
    __shared__ float t[64][65];
    const int tx = threadIdx.x & 15, ty = threadIdx.x >> 4;
#pragma unroll
    for (int i = 0; i < 4; ++i) {
        int c = c0 + ty + i * 16;
        float rs = stats[256 + b * 32 + (c >> 4)];
        float ga = gng[c] * rs;
        float be = gnb[c] - stats[b * 32 + (c >> 4)] * ga;
        float4 v = *(const float4*)(x + ((long)b * 512 + c) * 1024 + s0 + tx * 4);
        t[ty + i * 16][tx * 4 + 0] = v.x * ga + be;
        t[ty + i * 16][tx * 4 + 1] = v.y * ga + be;
        t[ty + i * 16][tx * 4 + 2] = v.z * ga + be;
        t[ty + i * 16][tx * 4 + 3] = v.w * ga + be;
    }
    __syncthreads();
#pragma unroll
    for (int i = 0; i < 4; ++i) {
        int s = s0 + ty + i * 16;
        ushort4 o;
        o.x = f2b_us(t[tx * 4 + 0][ty + i * 16]);
        o.y = f2b_us(t[tx * 4 + 1][ty + i * 16]);
        o.z = f2b_us(t[tx * 4 + 2][ty + i * 16]);
        o.w = f2b_us(t[tx * 4 + 3][ty + i * 16]);
        *(ushort4*)(xt + ((long)b * 1024 + s) * 512 + c0 + tx * 4) = o;
    }
}

// ---------------------------------------------------------------- LayerNorm
__global__ __launch_bounds__(256) void ln_k(const bf16* __restrict__ in,
                                            const float* __restrict__ g,
                                            const float* __restrict__ bvec,
                                            bf16* __restrict__ out) {
    long row = blockIdx.x;
    const bf16* p = in + row * 512;
    int tid = threadIdx.x;
    float v0 = b2f_us(__builtin_bit_cast(unsigned short, p[tid]));
    float v1 = b2f_us(__builtin_bit_cast(unsigned short, p[tid + 256]));
    float s = v0 + v1, sq = v0 * v0 + v1 * v1;
#pragma unroll
    for (int off = 32; off; off >>= 1) {
        s += __shfl_down(s, off);
        sq += __shfl_down(sq, off);
    }
    __shared__ float r0[4], r1[4];
    if ((tid & 63) == 0) { r0[tid >> 6] = s; r1[tid >> 6] = sq; }
    __syncthreads();
    s = r0[0] + r0[1] + r0[2] + r0[3];
    sq = r1[0] + r1[1] + r1[2] + r1[3];
    float mu = s * (1.f / 512.f);
    float var = sq * (1.f / 512.f) - mu * mu;
    float rs = rsqrtf(var + 1e-5f);
    out[row * 512 + tid] = __float2bfloat16((v0 - mu) * rs * g[tid] + bvec[tid]);
    out[row * 512 + tid + 256] =
        __float2bfloat16((v1 - mu) * rs * g[tid + 256] + bvec[tid + 256]);
}

// ---------------------------------------------------------------- unified MFMA GEMM
// m97 structure: 128x128 tile, BK=64, single 32KB LDS buffer,
// per K-step: stage -> vmcnt(0) drain -> barrier -> compute -> barrier.
// A (M x K) lda; B (N x K) ldb; C (M x N) ldc.
template <bool HASBIAS, bool HASRES>
__global__ __launch_bounds__(256, 2) void mm_k(
    const bf16* __restrict__ A, const bf16* __restrict__ Bw,
    const float* __restrict__ bias, const bf16* __restrict__ res,
    bf16* __restrict__ C, int lda, int ldb, int ldc, int NT) {
    __shared__ bf16 sA[8192];
    __shared__ bf16 sB[8192];
    const int lane = threadIdx.x & 63, wave = threadIdx.x >> 6;
    const int lr = lane & 15, lg = lane >> 4;
    const int wm = wave >> 1, wn = wave & 1;
    const int m0 = blockIdx.y * 128, n0 = blockIdx.x * 128;

    f32x4 acc[4][4];
#pragma unroll
    for (int i = 0; i < 4; ++i)
#pragma unroll
        for (int j = 0; j < 4; ++j) acc[i][j] = (f32x4){0.f, 0.f, 0.f, 0.f};

    for (int t = 0; t < NT; ++t) {
        const int k0 = t * 64;
        // stage: 16 A-subtiles + 16 B-subtiles, 8 gloads per wave
#pragma unroll
        for (int q = 0; q < 4; ++q) {
            int st = wave * 4 + q;           // 0..15
            int kh = st >> 3, sm = st & 7;
            gload16(A + (long)(m0 + sm * 16 + lr) * lda + k0 + kh * 32 + lg * 8,
                    &sA[st << 9]);
            gload16(Bw + (long)(n0 + sm * 16 + lr) * ldb + k0 + kh * 32 + lg * 8,
                    &sB[st << 9]);
        }
        asm volatile("s_waitcnt vmcnt(0) lgkmcnt(0)" ::: "memory");
        __builtin_amdgcn_s_barrier();
#pragma unroll
        for (int kh = 0; kh < 2; ++kh) {
            bf16x8 af[4], bfr[4];
#pragma unroll
            for (int i = 0; i < 4; ++i)
                af[i] = ldfrag(&sA[((kh * 8 + wm * 4 + i) << 9) + lane * 8]);
#pragma unroll
            for (int j = 0; j < 4; ++j)
                bfr[j] = ldfrag(&sB[((kh * 8 + wn * 4 + j) << 9) + lane * 8]);
#pragma unroll
            for (int i = 0; i < 4; ++i)
#pragma unroll
                for (int j = 0; j < 4; ++j)
                    acc[i][j] = mfma16(af[i], bfr[j], acc[i][j]);
        }
        __builtin_amdgcn_s_barrier();
    }

#pragma unroll
    for (int i = 0; i < 4; ++i) {
        int row = m0 + wm * 64 + i * 16 + lg * 4;
#pragma unroll
        for (int j = 0; j < 4; ++j) {
            int col = n0 + wn * 64 + j * 16 + lr;
            float bv = HASBIAS ? bias[col] : 0.f;
#pragma unroll
            for (int r = 0; r < 4; ++r) {
                float v = acc[i][j][r] + bv;
                if (HASRES)
                    v += b2f_us(__builtin_bit_cast(unsigned short,
                             res[(long)(row + r) * ldc + col]));
                C[(long)(row + r) * ldc + col] = __float2bfloat16(v);
            }
        }
    }
}

// ---------------------------------------------------------------- MFMA GEGLU GEMM (same m97 loop)
// out tile 128 x 64; B tile = 64 val cols + 64 gate cols.
__global__ __launch_bounds__(256, 2) void mm_geglu_k(
    const bf16* __restrict__ A, const bf16* __restrict__ Bv,
    const bf16* __restrict__ Bg, const float* __restrict__ bias,
    bf16* __restrict__ C, int NT) {
    __shared__ bf16 sA[8192];
    __shared__ bf16 sB[8192];
    const int lane = threadIdx.x & 63, wave = threadIdx.x >> 6;
    const int lr = lane & 15, lg = lane >> 4;
    const int wm = wave >> 1, wn = wave & 1;
    const int m0 = blockIdx.y * 128, n0 = blockIdx.x * 64;

    f32x4 accv[4][2], accg[4][2];
#pragma unroll
    for (int i = 0; i < 4; ++i)
#pragma unroll
        for (int j = 0; j < 2; ++j) {
            accv[i][j] = (f32x4){0.f, 0.f, 0.f, 0.f};
            accg[i][j] = (f32x4){0.f, 0.f, 0.f, 0.f};
        }

    for (int t = 0; t < NT; ++t) {
        const int k0 = t * 64;
#pragma unroll
        for (int q = 0; q < 4; ++q) {
            int st = wave * 4 + q;
            int kh = st >> 3, sm = st & 7;
            gload16(A + (long)(m0 + sm * 16 + lr) * 512 + k0 + kh * 32 + lg * 8,
                    &sA[st << 9]);
            const bf16* bsrc = (sm < 4) ? Bv : Bg;
            int sn = sm & 3;
            gload16(bsrc + (long)(n0 + sn * 16 + lr) * 512 + k0 + kh * 32 + lg * 8,
                    &sB[st << 9]);
        }
        asm volatile("s_waitcnt vmcnt(0) lgkmcnt(0)" ::: "memory");
        __builtin_amdgcn_s_barrier();
#pragma unroll
        for (int kh = 0; kh < 2; ++kh) {
            bf16x8 af[4], bv_[2], bg_[2];
#pragma unroll
            for (int i = 0; i < 4; ++i)
                af[i] = ldfrag(&sA[((kh * 8 + wm * 4 + i) << 9) + lane * 8]);
#pragma unroll
            for (int j = 0; j < 2; ++j) {
                bv_[j] = ldfrag(&sB[((kh * 8 + wn * 2 + j) << 9) + lane * 8]);
                bg_[j] = ldfrag(&sB[((kh * 8 + 4 + wn * 2 + j) << 9) + lane * 8]);
            }
#pragma unroll
            for (int i = 0; i < 4; ++i)
#pragma unroll
                for (int j = 0; j < 2; ++j) {
                    accv[i][j] = mfma16(af[i], bv_[j], accv[i][j]);
                    accg[i][j] = mfma16(af[i], bg_[j], accg[i][j]);
                }
        }
        __builtin_amdgcn_s_barrier();
    }

#pragma unroll
    for (int i = 0; i < 4; ++i) {
        int row = m0 + wm * 64 + i * 16 + lg * 4;
#pragma unroll
        for (int j = 0; j < 2; ++j) {
            int col = n0 + (wn * 2 + j) * 16 + lr;
            float bv = bias[col], bg2 = bias[2048 + col];
#pragma unroll
            for (int r = 0; r < 4; ++r) {
                float v = accv[i][j][r] + bv;
                float g = accg[i][j][r] + bg2;
                float gl = 0.5f * g * (1.f + erff(g * 0.70710678118654752f));
                C[(long)(row + r) * 2048 + col] = __float2bfloat16(v * gl);
            }
        }
    }
}

// ---------------------------------------------------------------- V transpose (LDS-tiled, coalesced)
__global__ __launch_bounds__(256) void vtrans_k(const bf16* __restrict__ qkv,
                                                bf16* __restrict__ vt) {
    const int bh = blockIdx.y;
    const int b = bh >> 3, h = bh & 7;
    const int s0 = blockIdx.x * 64;
    __shared__ bf16 tl[64][72];
    const int sl = threadIdx.x >> 2, q = threadIdx.x & 3;
    const bf16* src = qkv + ((long)b * 1024 + s0 + sl) * 1536 + 1024 + h * 64;
    *(shortx8*)&tl[sl][q * 8] = *(const shortx8*)(src + q * 8);
    *(shortx8*)&tl[sl][32 + q * 8] = *(const shortx8*)(src + 32 + q * 8);
    __syncthreads();
    const int dl = threadIdx.x >> 2;
    bf16* dst = vt + ((long)bh * 64 + dl) * 1024 + s0;
#pragma unroll
    for (int c = 0; c < 2; ++c) {
        int sb = c * 32 + q * 8;
        shortx8 o;
#pragma unroll
        for (int i = 0; i < 8; ++i)
            o[i] = __builtin_bit_cast(short, tl[sb + i][dl]);
        *(shortx8*)(dst + sb) = o;
    }
}

// ---------------------------------------------------------------- MFMA flash attention
// grid (8, 8, 8); 4 waves x 32 q-rows; single-buffer m97-style K/V staging.
__global__ __launch_bounds__(256) void attn_mfma_k(const bf16* __restrict__ qkv,
                                                   const bf16* __restrict__ vt,
                                                   bf16* __restrict__ o) {
    const int wave = threadIdx.x >> 6, lane = threadIdx.x & 63;
    const int lr = lane & 15, lg = lane >> 4;
    const int h = blockIdx.y, b = blockIdx.z;
    const int q0 = blockIdx.x * 128 + wave * 32;
    __shared__ bf16 sKV[8192];         // 8 K subtiles + 8 V subtiles
    __shared__ bf16 plds[4][16][72];   // per-wave P tile
    bf16* pl = &plds[wave][0][0];
    const bf16* qbase = qkv + (long)b * 1024 * 1536 + h * 64;
    const bf16* kbase = qbase + 512;
    const bf16* vbase = vt + ((long)(b * 8 + h) * 64) * 1024;

    bf16x8 qf[2][2];
#pragma unroll
    for (int s = 0; s < 2; ++s) {
        const bf16* qp = qbase + (long)(q0 + s * 16 + lr) * 1536 + lg * 8;
#pragma unroll
        for (int c = 0; c < 2; ++c) {
            shortx8 raw = *(const shortx8*)(qp + c * 32);
            shortx8 sc;
#pragma unroll
            for (int j = 0; j < 8; ++j)
                sc[j] = __builtin_bit_cast(short,
                    f2b_us(b2f_us((unsigned short)raw[j]) * 0.125f));
            qf[s][c] = __builtin_bit_cast(bf16x8, sc);
        }
    }

    f32x4 of[2][4];
    float mrow[2][4], lrow[2][4];
#pragma unroll
    for (int s = 0; s < 2; ++s)
#pragma unroll
        for (int r = 0; r < 4; ++r) {
            of[s][r] = (f32x4){0.f, 0.f, 0.f, 0.f};
            mrow[s][r] = -1e30f;
            lrow[s][r] = 0.f;
        }

    for (int t = 0; t < 16; ++t) {
        const int kv0 = t * 64;
#pragma unroll
        for (int q = 0; q < 4; ++q) {
            int st = wave * 4 + q;
            const bf16* src;
            if (st < 8)
                src = kbase + (long)(kv0 + (st >> 1) * 16 + lr) * 1536 +
                      (st & 1) * 32 + lg * 8;
            else
                src = vbase + (long)(((st - 8) >> 1) * 16 + lr) * 1024 + kv0 +
                      (st & 1) * 32 + lg * 8;
            gload16(src, &sKV[st << 9]);
        }
        asm volatile("s_waitcnt vmcnt(0) lgkmcnt(0)" ::: "memory");
        __builtin_amdgcn_s_barrier();

        f32x4 sf[2][4];
        __builtin_amdgcn_s_setprio(1);
#pragma unroll
        for (int kt = 0; kt < 4; ++kt) {
            bf16x8 k0f = ldfrag(&sKV[(kt * 2) * 512 + lane * 8]);
            bf16x8 k1f = ldfrag(&sKV[(kt * 2 + 1) * 512 + lane * 8]);
#pragma unroll
            for (int s = 0; s < 2; ++s) {
                f32x4 z = {0.f, 0.f, 0.f, 0.f};
                z = mfma16(qf[s][0], k0f, z);
                z = mfma16(qf[s][1], k1f, z);
                sf[s][kt] = z;
            }
        }
        __builtin_amdgcn_s_setprio(0);

        bf16x8 pa[2][2];
#pragma unroll
        for (int s = 0; s < 2; ++s) {
            float mt[4];
#pragma unroll
            for (int r = 0; r < 4; ++r)
                mt[r] = fmaxf(fmaxf(sf[s][0][r], sf[s][1][r]),
                              fmaxf(sf[s][2][r], sf[s][3][r]));
#pragma unroll
            for (int m = 1; m < 16; m <<= 1)
#pragma unroll
                for (int r = 0; r < 4; ++r)
                    mt[r] = fmaxf(mt[r], __shfl_xor(mt[r], m));
            float al[4];
#pragma unroll
            for (int r = 0; r < 4; ++r) {
                float mn = fmaxf(mrow[s][r], mt[r]);
                al[r] = __expf(mrow[s][r] - mn);
                mrow[s][r] = mn;
            }
            float psum[4] = {0.f, 0.f, 0.f, 0.f};
#pragma unroll
            for (int kt = 0; kt < 4; ++kt)
#pragma unroll
                for (int r = 0; r < 4; ++r) {
                    float p = __expf(sf[s][kt][r] - mrow[s][r]);
                    psum[r] += p;
                    pl[(lg * 4 + r) * 72 + kt * 16 + lr] = __float2bfloat16(p);
                }
#pragma unroll
            for (int m = 1; m < 16; m <<= 1)
#pragma unroll
                for (int r = 0; r < 4; ++r)
                    psum[r] += __shfl_xor(psum[r], m);
#pragma unroll
            for (int r = 0; r < 4; ++r)
                lrow[s][r] = lrow[s][r] * al[r] + psum[r];
#pragma unroll
            for (int dt = 0; dt < 4; ++dt)
#pragma unroll
                for (int r = 0; r < 4; ++r) of[s][dt][r] *= al[r];
            pa[s][0] = ldfrag(pl + lr * 72 + lg * 8);
            pa[s][1] = ldfrag(pl + lr * 72 + 32 + lg * 8);
        }
        __builtin_amdgcn_s_setprio(1);
#pragma unroll
        for (int dt = 0; dt < 4; ++dt) {
            bf16x8 v0f = ldfrag(&sKV[(8 + dt * 2) * 512 + lane * 8]);
            bf16x8 v1f = ldfrag(&sKV[(8 + dt * 2 + 1) * 512 + lane * 8]);
#pragma unroll
            for (int s = 0; s < 2; ++s) {
                of[s][dt] = mfma16(pa[s][0], v0f, of[s][dt]);
                of[s][dt] = mfma16(pa[s][1], v1f, of[s][dt]);
            }
        }
        __builtin_amdgcn_s_setprio(0);
        __builtin_amdgcn_s_barrier();
    }

#pragma unroll
    for (int s = 0; s < 2; ++s) {
        bf16* op = o + ((long)b * 1024 + q0 + s * 16 + lg * 4) * 512 + h * 64 + lr;
#pragma unroll
        for (int r = 0; r < 4; ++r) {
            float inv = 1.f / lrow[s][r];
#pragma unroll
            for (int dt = 0; dt < 4; ++dt)
                op[(long)r * 512 + dt * 16] = __float2bfloat16(of[s][dt][r] * inv);
        }
    }
}

// ---------------------------------------------------------------- conv_out epilogue
__global__ __launch_bounds__(256) void outepi_k(const bf16* __restrict__ tmp,
                                                const float* __restrict__ bcout,
                                                const float* __restrict__ x,
                                                float* __restrict__ out) {
    const int b = blockIdx.z;
    const int o0 = blockIdx.y * 64, s0 = blockIdx.x * 64;
    __shared__ float t[64][65];
    const int tx = threadIdx.x & 15, ty = threadIdx.x >> 4;
#pragma unroll
    for (int i = 0; i < 4; ++i) {
        int s = s0 + ty + i * 16;
        float4 v = ld4(tmp + ((long)b * 1024 + s) * 512 + o0 + tx * 4);
        t[ty + i * 16][tx * 4 + 0] = v.x;
        t[ty + i * 16][tx * 4 + 1] = v.y;
        t[ty + i * 16][tx * 4 + 2] = v.z;
        t[ty + i * 16][tx * 4 + 3] = v.w;
    }
    __syncthreads();
#pragma unroll
    for (int i = 0; i < 4; ++i) {
        int o = o0 + ty + i * 16;
        long idx = ((long)b * 512 + o) * 1024 + s0 + tx * 4;
        float4 xr = *(const float4*)(x + idx);
        float bc = bcout[o];
        float4 w;
        w.x = t[tx * 4 + 0][ty + i * 16] + bc + xr.x;
        w.y = t[tx * 4 + 1][ty + i * 16] + bc + xr.y;
        w.z = t[tx * 4 + 2][ty + i * 16] + bc + xr.z;
        w.w = t[tx * 4 + 3][ty + i * 16] + bc + xr.w;
        *(float4*)(out + idx) = w;
    }
}

// ---------------------------------------------------------------- launcher
extern "C" void kernel_launch(void* const* d_in, const int* in_sizes, int n_in,
                              void* d_out, int out_size, void* d_ws, size_t ws_size,
                              hipStream_t stream) {
    const float* x = (const float*)d_in[0];
    const float* gn_g = (const float*)d_in[1];
    const float* gn_b = (const float*)d_in[2];
    const float* w_cin = (const float*)d_in[3];
    const float* b_cin = (const float*)d_in[4];
    const float* ln1_g = (const float*)d_in[5];
    const float* ln1_b = (const float*)d_in[6];
    const float* qkv1w = (const float*)d_in[7];
    const float* out1_w = (const float*)d_in[8];
    const float* out1_b = (const float*)d_in[9];
    const float* ln2_g = (const float*)d_in[10];
    const float* ln2_b = (const float*)d_in[11];
    const float* qkv2w = (const float*)d_in[12];
    const float* out2_w = (const float*)d_in[13];
    const float* out2_b = (const float*)d_in[14];
    const float* ln3_g = (const float*)d_in[15];
    const float* ln3_b = (const float*)d_in[16];
    const float* g1_w = (const float*)d_in[17];
    const float* g1_b = (const float*)d_in[18];
    const float* g2_w = (const float*)d_in[19];
    const float* g2_b = (const float*)d_in[20];
    const float* w_cout = (const float*)d_in[21];
    const float* b_cout = (const float*)d_in[22];
    float* out = (float*)d_out;

    char* ws = (char*)d_ws;
    float* stats = (float*)ws;
    bf16* wq1 = (bf16*)(ws + 4096);          // (1536,512)
    bf16* wo1 = wq1 + 1536 * 512;            // (512,512)
    bf16* wq2 = wo1 + 512 * 512;             // (1536,512)
    bf16* wo2 = wq2 + 1536 * 512;            // (512,512)
    bf16* wg1 = wo2 + 512 * 512;             // (4096,512)
    bf16* wg2 = wg1 + 4096 * 512;            // (512,2048)
    bf16* wci = wg2 + 512 * 2048;            // (512,512)
    bf16* wco = wci + 512 * 512;             // (512,512)
    bf16* h = wco + 512 * 512;               // (8192,512)
    bf16* h2 = h + (size_t)8192 * 512;
    bf16* lnb = h2 + (size_t)8192 * 512;     // also xt / vt / tmp
    bf16* qkv = lnb + (size_t)8192 * 512;    // (8192,1536)
    bf16* obuf = qkv + (size_t)8192 * 1536;  // (8192,512)
    bf16* gg = qkv;                          // (8192,2048) reuses qkv+obuf
    bf16* vt = lnb;

    WJobs jobs;
    jobs.j[0] = {qkv1w, wq1, 512, 1536, 0, 1};
    jobs.j[1] = {out1_w, wo1, 512, 512, 768, 1};
    jobs.j[2] = {qkv2w, wq2, 512, 1536, 1024, 1};
    jobs.j[3] = {out2_w, wo2, 512, 512, 1792, 1};
    jobs.j[4] = {g1_w, wg1, 512, 4096, 2048, 1};
    jobs.j[5] = {g2_w, wg2, 2048, 512, 4096, 1};
    jobs.j[6] = {w_cin, wci, 512, 512, 5120, 0};
    jobs.j[7] = {w_cout, wco, 512, 512, 5376, 0};
    wconv_all<<<5632, 256, 0, stream>>>(jobs);

    gn_stats_k<<<256, 256, 0, stream>>>(x, stats);
    gnxt_k<<<dim3(16, 8, 8), 256, 0, stream>>>(x, stats, gn_g, gn_b, lnb);
    // conv_in
    mm_k<true, false><<<dim3(4, 64), 256, 0, stream>>>(
        lnb, wci, b_cin, nullptr, h, 512, 512, 512, 8);

    ln_k<<<8192, 256, 0, stream>>>(h, ln1_g, ln1_b, lnb);
    mm_k<false, false><<<dim3(12, 64), 256, 0, stream>>>(
        lnb, wq1, nullptr, nullptr, qkv, 512, 512, 1536, 8);
    vtrans_k<<<dim3(16, 64), 256, 0, stream>>>(qkv, vt);
    attn_mfma_k<<<dim3(8, 8, 8), 256, 0, stream>>>(qkv, vt, obuf);
    mm_k<true, true><<<dim3(4, 64), 256, 0, stream>>>(
        obuf, wo1, out1_b, h, h2, 512, 512, 512, 8);

    ln_k<<<8192, 256, 0, stream>>>(h2, ln2_g, ln2_b, lnb);
    mm_k<false, false><<<dim3(12, 64), 256, 0, stream>>>(
        lnb, wq2, nullptr, nullptr, qkv, 512, 512, 1536, 8);
    vtrans_k<<<dim3(16, 64), 256, 0, stream>>>(qkv, vt);
    attn_mfma_k<<<dim3(8, 8, 8), 256, 0, stream>>>(qkv, vt, obuf);
    mm_k<true, true><<<dim3(4, 64), 256, 0, stream>>>(
        obuf, wo2, out2_b, h2, h, 512, 512, 512, 8);

    ln_k<<<8192, 256, 0, stream>>>(h, ln3_g, ln3_b, lnb);
    mm_geglu_k<<<dim3(32, 64), 256, 0, stream>>>(
        lnb, wg1, wg1 + (size_t)2048 * 512, g1_b, gg, 8);
    mm_k<true, true><<<dim3(4, 64), 256, 0, stream>>>(
        gg, wg2, g2_b, h, h2, 2048, 2048, 512, 32);

    // conv_out: tmp = h2 @ w_cout^T
    mm_k<false, false><<<dim3(4, 64), 256, 0, stream>>>(
        h2, wco, nullptr, nullptr, lnb, 512, 512, 512, 8);
    outepi_k<<<dim3(16, 8, 8), 256, 0, stream>>>(lnb, b_cout, x, out);
}